// Round 3
// baseline (392.310 us; speedup 1.0000x reference)
//
#include <hip/hip_runtime.h>

#define HIDN 512
#define NHEAD 8
#define DHEAD 64
#define NB 4
#define NL 256
#define NROW 1024   // NB*NL

// 2*log2(e): exp(2y) = exp2(y * SCALE2)
#define SCALE2 2.8853900817779268f
#define LOG2E  1.4426950408889634f

// workspace layout (float offsets)
#define WS_WQF 0
#define WS_WKF (WS_WQF + HIDN*HIDN)
#define WS_BQF (WS_WKF + HIDN*HIDN)
#define WS_BKF (WS_BQF + HIDN)
#define WS_QT  (WS_BKF + HIDN)
#define WS_KT  (WS_QT + NROW*HIDN)
#define WS_VH  (WS_KT + NROW*HIDN)
#define WS_X   (WS_VH + NROW*HIDN)
// V bf16 fragments: reuses WS_WQF (dead after proj_gemm; v_frag launches after proj_gemm)
#define WS_VF  WS_WQF   // 32bh*32tile*64lane*8j shorts = 1 MB = 256K floats (fits in WQF's 256K)

typedef __attribute__((ext_vector_type(4))) float f32x4;
typedef __attribute__((ext_vector_type(8))) short bf16x8;

__device__ __forceinline__ short f2bf(float x) {
  unsigned u = __float_as_uint(x);
  u += 0x7fffu + ((u >> 16) & 1u);   // RNE
  return (short)(u >> 16);
}

// ---------------- Kernel A: fold W1/W2 (and the 2*log2e prescale) into Wq/Wk ----------------
__global__ __launch_bounds__(256) void fuse_weights(
    const float* __restrict__ Wq, const float* __restrict__ bq,
    const float* __restrict__ Wk, const float* __restrict__ bk,
    const float* __restrict__ W1, const float* __restrict__ b1,
    const float* __restrict__ W2, const float* __restrict__ b2,
    float* __restrict__ ws)
{
  const int h  = blockIdx.y >> 2;
  const int ig = blockIdx.y & 3;       // 16-row group within head
  const int c0 = blockIdx.x * 128;
  const int which = blockIdx.z;
  const float* Wsrc = which ? Wk : Wq;
  const float* bsrc = which ? bk : bq;
  const float* Wt   = which ? W2 : W1;
  const float* bt   = which ? b2 : b1;
  float* Wout = ws + (which ? WS_WKF : WS_WQF);
  float* bout = ws + (which ? WS_BKF : WS_BQF);

  __shared__ float Wtl[16][68];
  for (int t = threadIdx.x; t < 16*64; t += 256)
    Wtl[t >> 6][t & 63] = Wt[(ig*16 + (t >> 6))*64 + (t & 63)];
  __syncthreads();

  const int c  = c0 + (threadIdx.x & 127);
  const int i0 = (threadIdx.x >> 7) * 8;   // local row base (0 or 8)
  float acc[8];
#pragma unroll
  for (int ii = 0; ii < 8; ++ii) acc[ii] = 0.f;

  for (int j0 = 0; j0 < 64; j0 += 4) {
    const float s0 = Wsrc[(h*64 + j0 + 0)*HIDN + c];
    const float s1 = Wsrc[(h*64 + j0 + 1)*HIDN + c];
    const float s2 = Wsrc[(h*64 + j0 + 2)*HIDN + c];
    const float s3 = Wsrc[(h*64 + j0 + 3)*HIDN + c];
#pragma unroll
    for (int ii = 0; ii < 8; ++ii) {
      const float4 wv = *reinterpret_cast<const float4*>(&Wtl[i0+ii][j0]);
      float a = acc[ii];
      a = fmaf(wv.x, s0, a);
      a = fmaf(wv.y, s1, a);
      a = fmaf(wv.z, s2, a);
      a = fmaf(wv.w, s3, a);
      acc[ii] = a;
    }
  }
#pragma unroll
  for (int ii = 0; ii < 8; ++ii)
    Wout[(h*64 + ig*16 + i0 + ii)*HIDN + c] = acc[ii] * SCALE2;

  if (blockIdx.x == 0 && threadIdx.x < 16) {
    const int il = threadIdx.x;
    float a = bt[ig*16 + il];
    for (int j = 0; j < 64; ++j)
      a = fmaf(Wtl[il][j], bsrc[h*64 + j], a);
    bout[h*64 + ig*16 + il] = a * SCALE2;
  }
}

// ---------------- proj GEMM: C = A @ W^T + bias, 64x64 tile, 4x4 micro, head-major out ----
__global__ __launch_bounds__(256) void proj_gemm(
    const float* __restrict__ q_in, const float* __restrict__ k_in, const float* __restrict__ v_in,
    const float* __restrict__ Wv, const float* __restrict__ bv, float* __restrict__ ws)
{
  const int z = blockIdx.z;
  const float* A; const float* W; const float* bias; float* C;
  if (z == 0)      { A = q_in; W = ws + WS_WQF; bias = ws + WS_BQF; C = ws + WS_QT; }
  else if (z == 1) { A = k_in; W = ws + WS_WKF; bias = ws + WS_BKF; C = ws + WS_KT; }
  else             { A = v_in; W = Wv;          bias = bv;          C = ws + WS_VH; }

  const int row0 = blockIdx.y * 64;
  const int col0 = blockIdx.x * 64;
  __shared__ float As[16][72];
  __shared__ float Bs[16][72];
  const int tid = threadIdx.x;
  const int tx = tid & 15;    // 4 cols each
  const int ty = tid >> 4;    // 4 rows each
  float acc[4][4];
#pragma unroll
  for (int i = 0; i < 4; ++i)
#pragma unroll
    for (int j = 0; j < 4; ++j) acc[i][j] = 0.f;

  const int srow = tid >> 2, kq = tid & 3;
  for (int k0 = 0; k0 < HIDN; k0 += 16) {
    {
      const float4 a4 = *reinterpret_cast<const float4*>(&A[(row0+srow)*HIDN + k0 + kq*4]);
      As[kq*4+0][srow] = a4.x; As[kq*4+1][srow] = a4.y;
      As[kq*4+2][srow] = a4.z; As[kq*4+3][srow] = a4.w;
      const float4 w4 = *reinterpret_cast<const float4*>(&W[(col0+srow)*HIDN + k0 + kq*4]);
      Bs[kq*4+0][srow] = w4.x; Bs[kq*4+1][srow] = w4.y;
      Bs[kq*4+2][srow] = w4.z; Bs[kq*4+3][srow] = w4.w;
    }
    __syncthreads();
#pragma unroll
    for (int kk = 0; kk < 16; ++kk) {
      const float4 av = *reinterpret_cast<const float4*>(&As[kk][ty*4]);
      const float4 bw = *reinterpret_cast<const float4*>(&Bs[kk][tx*4]);
      const float a_[4] = {av.x, av.y, av.z, av.w};
      const float b_[4] = {bw.x, bw.y, bw.z, bw.w};
#pragma unroll
      for (int i = 0; i < 4; ++i)
#pragma unroll
        for (int j = 0; j < 4; ++j)
          acc[i][j] = fmaf(a_[i], b_[j], acc[i][j]);
    }
    __syncthreads();
  }
  const int col = col0 + tx*4;
  const float4 b4 = *reinterpret_cast<const float4*>(&bias[col]);
  const int hh = col >> 6, d = col & 63;
#pragma unroll
  for (int i = 0; i < 4; ++i) {
    const int row = row0 + ty*4 + i;
    const int b = row >> 8, l = row & 255;
    float4 v;
    v.x = acc[i][0] + b4.x; v.y = acc[i][1] + b4.y;
    v.z = acc[i][2] + b4.z; v.w = acc[i][3] + b4.w;
    *reinterpret_cast<float4*>(&C[(((b*NHEAD + hh)*NL) + l)*DHEAD + d]) = v;
  }
}

// ---------------- v_frag: VH (head-major f32) -> bf16 MFMA B-fragments in ws ----------------
// element (k,d) -> tile=(k>>5)*4+(d>>4); lane=((k>>3)&3)*16+(d&15); j=k&7
__global__ __launch_bounds__(256) void v_frag(float* __restrict__ ws)
{
  const int bh = blockIdx.y;
  const int pair = blockIdx.x * 256 + threadIdx.x;   // 0..2047
  const int tile = pair >> 6;
  const int lane = pair & 63;
  const int base_k = (tile >> 2) * 32 + (lane >> 4) * 8;
  const int d = (tile & 3) * 16 + (lane & 15);
  const float* V = ws + WS_VH + (bh * NL) * DHEAD;
  short o[8];
#pragma unroll
  for (int j = 0; j < 8; ++j)
    o[j] = f2bf(V[(base_k + j) * DHEAD + d]);
  short* dst = reinterpret_cast<short*>(ws + WS_VF) + ((bh * 32 + tile) * 64 + lane) * 8;
  *reinterpret_cast<bf16x8*>(dst) = *reinterpret_cast<const bf16x8*>(o);
}

// ---------------- out GEMM: 64x32 tile ----------------
__global__ __launch_bounds__(256) void out_gemm(
    const float* __restrict__ A, const float* __restrict__ W,
    const float* __restrict__ bias, float* __restrict__ C)
{
  const int row0 = blockIdx.y * 64;
  const int col0 = blockIdx.x * 32;
  __shared__ float As[16][72];
  __shared__ float Bs[16][40];
  const int tid = threadIdx.x;
  const int tx = tid & 15;
  const int ty = tid >> 4;
  float acc00=0,acc01=0,acc10=0,acc11=0,acc20=0,acc21=0,acc30=0,acc31=0;

  for (int k0 = 0; k0 < HIDN; k0 += 16) {
    {
      const int arow = tid >> 2, kq = tid & 3;
      const float4 a4 = *reinterpret_cast<const float4*>(&A[(row0+arow)*HIDN + k0 + kq*4]);
      As[kq*4+0][arow] = a4.x; As[kq*4+1][arow] = a4.y;
      As[kq*4+2][arow] = a4.z; As[kq*4+3][arow] = a4.w;
    }
    if (tid < 128) {
      const int wcol = tid >> 2, kq = tid & 3;
      const float4 w4 = *reinterpret_cast<const float4*>(&W[(col0+wcol)*HIDN + k0 + kq*4]);
      Bs[kq*4+0][wcol] = w4.x; Bs[kq*4+1][wcol] = w4.y;
      Bs[kq*4+2][wcol] = w4.z; Bs[kq*4+3][wcol] = w4.w;
    }
    __syncthreads();
#pragma unroll
    for (int kk = 0; kk < 16; ++kk) {
      const float4 av  = *reinterpret_cast<const float4*>(&As[kk][ty*4]);
      const float2 bv2 = *reinterpret_cast<const float2*>(&Bs[kk][tx*2]);
      acc00 = fmaf(av.x, bv2.x, acc00);
      acc01 = fmaf(av.x, bv2.y, acc01);
      acc10 = fmaf(av.y, bv2.x, acc10);
      acc11 = fmaf(av.y, bv2.y, acc11);
      acc20 = fmaf(av.z, bv2.x, acc20);
      acc21 = fmaf(av.z, bv2.y, acc21);
      acc30 = fmaf(av.w, bv2.x, acc30);
      acc31 = fmaf(av.w, bv2.y, acc31);
    }
    __syncthreads();
  }
  const int c = col0 + tx*2;
  const float b0 = bias[c], b1v = bias[c+1];
  const float v0[4] = {acc00+b0, acc10+b0, acc20+b0, acc30+b0};
  const float v1[4] = {acc01+b1v, acc11+b1v, acc21+b1v, acc31+b1v};
#pragma unroll
  for (int i = 0; i < 4; ++i) {
    const int row = row0 + ty*4 + i;
    *reinterpret_cast<float2*>(&C[row*HIDN + c]) = make_float2(v0[i], v1[i]);
  }
}

// ---------------- attn: energy + (no-max) softmax + MFMA PV ----------------
// grid (16 qtiles, 32 bh), 512 threads. Thread (h=tid>>8, lk=tid&255) owns key lk
// for q-rows h*8..h*8+7. Kt row lives in registers (one burst load).
__global__ __launch_bounds__(512, 4) void attn_kernel(
    const float* __restrict__ ws, const float* __restrict__ va_w,
    float* __restrict__ attn_out, float* __restrict__ X)
{
  const int qt = blockIdx.x;
  const int bh = blockIdx.y;
  const int tid = threadIdx.x;

  __shared__ __align__(16) short aLb[8][64][8];      // 8 KB  P as bf16 A-fragments
  __shared__ __align__(16) float Qtl[16][64];        // 4 KB
  __shared__ __align__(16) float vaS[64];
  __shared__ __align__(16) float reds[2][4][8];

  const float* Qt  = ws + WS_QT + (bh*NL + qt*16)*DHEAD;
  const float* KtB = ws + WS_KT + bh*NL*DHEAD;
  const short* VF  = reinterpret_cast<const short*>(ws + WS_VF) + bh*32*64*8;

  if (tid < 256)
    reinterpret_cast<float4*>(Qtl)[tid] = reinterpret_cast<const float4*>(Qt)[tid];
  if (tid < 64) vaS[tid] = -2.0f * va_w[tid];

  const int h  = tid >> 8;
  const int lk = tid & 255;
  const int wv = lk >> 6;
  const int l  = lk & 63;

  // Kt row -> registers, one contiguous burst (L1-friendly, no mid-loop refetch)
  float kreg[64];
#pragma unroll
  for (int d0 = 0; d0 < 64; d0 += 4)
    *reinterpret_cast<float4*>(&kreg[d0]) =
        *reinterpret_cast<const float4*>(&KtB[lk*DHEAD + d0]);
  __syncthreads();

  float acc[8];
#pragma unroll
  for (int qi = 0; qi < 8; ++qi) acc[qi] = 0.f;

#pragma unroll
  for (int d0 = 0; d0 < 64; d0 += 4) {
    const float4 va4 = *reinterpret_cast<const float4*>(&vaS[d0]);
    const float k0 = kreg[d0+0], k1 = kreg[d0+1], k2 = kreg[d0+2], k3 = kreg[d0+3];
#pragma unroll
    for (int qi = 0; qi < 8; ++qi) {
      const float4 qv = *reinterpret_cast<const float4*>(&Qtl[h*8+qi][d0]);
      float a = acc[qi];
      a = fmaf(va4.x, __builtin_amdgcn_rcpf(1.0f + __builtin_amdgcn_exp2f(qv.x + k0)), a);
      a = fmaf(va4.y, __builtin_amdgcn_rcpf(1.0f + __builtin_amdgcn_exp2f(qv.y + k1)), a);
      a = fmaf(va4.z, __builtin_amdgcn_rcpf(1.0f + __builtin_amdgcn_exp2f(qv.z + k2)), a);
      a = fmaf(va4.w, __builtin_amdgcn_rcpf(1.0f + __builtin_amdgcn_exp2f(qv.w + k3)), a);
      acc[qi] = a;
    }
  }

  // p = exp(e) (|e| <= ~2*sum|va| ~ 8 -> no max shift needed)
  float p[8];
#pragma unroll
  for (int qi = 0; qi < 8; ++qi)
    p[qi] = __builtin_amdgcn_exp2f(acc[qi] * LOG2E);

#pragma unroll
  for (int qi = 0; qi < 8; ++qi) {
    float s = p[qi];
#pragma unroll
    for (int off = 1; off < 64; off <<= 1)
      s += __shfl_xor(s, off);
    if (l == 0) reds[h][wv][qi] = s;
  }
  // publish P as bf16 A-fragments
  {
    const int kb = lk >> 5;
    const int lbase = ((lk >> 3) & 3) * 16;
    const int jb = lk & 7;
#pragma unroll
    for (int qi = 0; qi < 8; ++qi)
      aLb[kb][lbase + h*8 + qi][jb] = f2bf(p[qi]);
  }
  __syncthreads();

  // totals + attention output (f32 exact path)
  {
    f32x4 slo = {0.f,0.f,0.f,0.f}, shi = {0.f,0.f,0.f,0.f};
#pragma unroll
    for (int w2 = 0; w2 < 4; ++w2) {
      slo += *reinterpret_cast<const f32x4*>(&reds[h][w2][0]);
      shi += *reinterpret_cast<const f32x4*>(&reds[h][w2][4]);
    }
    float inv[8];
    inv[0] = __builtin_amdgcn_rcpf(slo.x); inv[1] = __builtin_amdgcn_rcpf(slo.y);
    inv[2] = __builtin_amdgcn_rcpf(slo.z); inv[3] = __builtin_amdgcn_rcpf(slo.w);
    inv[4] = __builtin_amdgcn_rcpf(shi.x); inv[5] = __builtin_amdgcn_rcpf(shi.y);
    inv[6] = __builtin_amdgcn_rcpf(shi.z); inv[7] = __builtin_amdgcn_rcpf(shi.w);
#pragma unroll
    for (int qi = 0; qi < 8; ++qi)
      attn_out[(bh*NL + qt*16 + h*8 + qi)*NL + lk] = p[qi] * inv[qi];

    // PV via MFMA: waves 0..3 (wid = d-block), V B-fragments straight from global (L2-hot)
    const int wid = tid >> 6;
    if (wid < 4) {
      f32x4 pacc = {0.f,0.f,0.f,0.f};
#pragma unroll
      for (int kb2 = 0; kb2 < 8; ++kb2) {
        const bf16x8 af  = *reinterpret_cast<const bf16x8*>(&aLb[kb2][l][0]);
        const bf16x8 bff = *reinterpret_cast<const bf16x8*>(&VF[((kb2*4 + wid)*64 + l)*8]);
        pacc = __builtin_amdgcn_mfma_f32_16x16x32_bf16(af, bff, pacc, 0, 0, 0);
      }
      const int b_ = bh >> 3, hh = bh & 7;
      const int colv = hh*DHEAD + wid*16 + (l & 15);
#pragma unroll
      for (int r = 0; r < 4; ++r) {
        const int row = (l >> 4)*4 + r;            // q index 0..15
        float stot = reds[row>>3][0][row&7] + reds[row>>3][1][row&7]
                   + reds[row>>3][2][row&7] + reds[row>>3][3][row&7];
        X[((b_*NL + qt*16 + row)*HIDN) + colv] = pacc[r] * __builtin_amdgcn_rcpf(stot);
      }
    }
  }
}

extern "C" void kernel_launch(void* const* d_in, const int* in_sizes, int n_in,
                              void* d_out, int out_size, void* d_ws, size_t ws_size,
                              hipStream_t stream) {
  const float* query = (const float*)d_in[0];
  const float* key   = (const float*)d_in[1];
  const float* value = (const float*)d_in[2];
  const float* Wq = (const float*)d_in[3];
  const float* bq = (const float*)d_in[4];
  const float* Wk = (const float*)d_in[5];
  const float* bk = (const float*)d_in[6];
  const float* Wv = (const float*)d_in[7];
  const float* bv = (const float*)d_in[8];
  const float* W1 = (const float*)d_in[9];
  const float* b1 = (const float*)d_in[10];
  const float* W2 = (const float*)d_in[11];
  const float* b2 = (const float*)d_in[12];
  const float* va_w = (const float*)d_in[13];
  const float* Wo = (const float*)d_in[15];
  const float* bo = (const float*)d_in[16];

  float* out = (float*)d_out;
  float* ws  = (float*)d_ws;
  float* attn = out + NROW*HIDN;   // output 1: attention [B,H,Lq,Lk]

  fuse_weights<<<dim3(4, 32, 2), 256, 0, stream>>>(Wq, bq, Wk, bk, W1, b1, W2, b2, ws);
  proj_gemm<<<dim3(8, 16, 3), 256, 0, stream>>>(query, key, value, Wv, bv, ws);
  v_frag<<<dim3(8, 32), 256, 0, stream>>>(ws);   // after proj (reads VH, overwrites dead WQF)
  attn_kernel<<<dim3(16, 32), 512, 0, stream>>>(ws, va_w, attn, ws + WS_X);
  out_gemm<<<dim3(16, 16), 256, 0, stream>>>(ws + WS_X, Wo, bo, out);
}

// Round 4
// 111.880 us; speedup vs baseline: 3.5065x; 3.5065x over previous
//
#include <hip/hip_runtime.h>

#define HIDN 512
#define NHEAD 8
#define DHEAD 64
#define NB 4
#define NL 256
#define NROW 1024   // NB*NL

// 2*log2(e): exp(2y) = exp2(y * SCALE2)
#define SCALE2 2.8853900817779268f
#define LOG2E  1.4426950408889634f

// workspace layout (float offsets)
#define WS_WQF 0
#define WS_WKF (WS_WQF + HIDN*HIDN)
#define WS_BQF (WS_WKF + HIDN*HIDN)
#define WS_BKF (WS_BQF + HIDN)
#define WS_QT  (WS_BKF + HIDN)
#define WS_KT  (WS_QT + NROW*HIDN)
#define WS_VH  (WS_KT + NROW*HIDN)
#define WS_X   (WS_VH + NROW*HIDN)
// V bf16 fragments: reuses WS_WQF (dead after proj_gemm; v_frag launches after proj_gemm)
#define WS_VF  WS_WQF   // 32bh*32tile*64lane*8j shorts = 1 MB (fits in WQF's 1 MB)

typedef __attribute__((ext_vector_type(4))) float f32x4;
typedef __attribute__((ext_vector_type(8))) short bf16x8;

__device__ __forceinline__ short f2bf(float x) {
  unsigned u = __float_as_uint(x);
  u += 0x7fffu + ((u >> 16) & 1u);   // RNE
  return (short)(u >> 16);
}

// ---------------- Kernel A: fold W1/W2 (and the 2*log2e prescale) into Wq/Wk ----------------
__global__ __launch_bounds__(256) void fuse_weights(
    const float* __restrict__ Wq, const float* __restrict__ bq,
    const float* __restrict__ Wk, const float* __restrict__ bk,
    const float* __restrict__ W1, const float* __restrict__ b1,
    const float* __restrict__ W2, const float* __restrict__ b2,
    float* __restrict__ ws)
{
  const int h  = blockIdx.y >> 2;
  const int ig = blockIdx.y & 3;       // 16-row group within head
  const int c0 = blockIdx.x * 128;
  const int which = blockIdx.z;
  const float* Wsrc = which ? Wk : Wq;
  const float* bsrc = which ? bk : bq;
  const float* Wt   = which ? W2 : W1;
  const float* bt   = which ? b2 : b1;
  float* Wout = ws + (which ? WS_WKF : WS_WQF);
  float* bout = ws + (which ? WS_BKF : WS_BQF);

  __shared__ float Wtl[16][68];
  for (int t = threadIdx.x; t < 16*64; t += 256)
    Wtl[t >> 6][t & 63] = Wt[(ig*16 + (t >> 6))*64 + (t & 63)];
  __syncthreads();

  const int c  = c0 + (threadIdx.x & 127);
  const int i0 = (threadIdx.x >> 7) * 8;   // local row base (0 or 8)
  float acc[8];
#pragma unroll
  for (int ii = 0; ii < 8; ++ii) acc[ii] = 0.f;

  for (int j0 = 0; j0 < 64; j0 += 4) {
    const float s0 = Wsrc[(h*64 + j0 + 0)*HIDN + c];
    const float s1 = Wsrc[(h*64 + j0 + 1)*HIDN + c];
    const float s2 = Wsrc[(h*64 + j0 + 2)*HIDN + c];
    const float s3 = Wsrc[(h*64 + j0 + 3)*HIDN + c];
#pragma unroll
    for (int ii = 0; ii < 8; ++ii) {
      const float4 wv = *reinterpret_cast<const float4*>(&Wtl[i0+ii][j0]);
      float a = acc[ii];
      a = fmaf(wv.x, s0, a);
      a = fmaf(wv.y, s1, a);
      a = fmaf(wv.z, s2, a);
      a = fmaf(wv.w, s3, a);
      acc[ii] = a;
    }
  }
#pragma unroll
  for (int ii = 0; ii < 8; ++ii)
    Wout[(h*64 + ig*16 + i0 + ii)*HIDN + c] = acc[ii] * SCALE2;

  if (blockIdx.x == 0 && threadIdx.x < 16) {
    const int il = threadIdx.x;
    float a = bt[ig*16 + il];
    for (int j = 0; j < 64; ++j)
      a = fmaf(Wtl[il][j], bsrc[h*64 + j], a);
    bout[h*64 + ig*16 + il] = a * SCALE2;
  }
}

// ---------------- proj GEMM: C = A @ W^T + bias, 64x64 tile, 4x4 micro, head-major out ----
__global__ __launch_bounds__(256) void proj_gemm(
    const float* __restrict__ q_in, const float* __restrict__ k_in, const float* __restrict__ v_in,
    const float* __restrict__ Wv, const float* __restrict__ bv, float* __restrict__ ws)
{
  const int z = blockIdx.z;
  const float* A; const float* W; const float* bias; float* C;
  if (z == 0)      { A = q_in; W = ws + WS_WQF; bias = ws + WS_BQF; C = ws + WS_QT; }
  else if (z == 1) { A = k_in; W = ws + WS_WKF; bias = ws + WS_BKF; C = ws + WS_KT; }
  else             { A = v_in; W = Wv;          bias = bv;          C = ws + WS_VH; }

  const int row0 = blockIdx.y * 64;
  const int col0 = blockIdx.x * 64;
  __shared__ float As[16][72];
  __shared__ float Bs[16][72];
  const int tid = threadIdx.x;
  const int tx = tid & 15;    // 4 cols each
  const int ty = tid >> 4;    // 4 rows each
  float acc[4][4];
#pragma unroll
  for (int i = 0; i < 4; ++i)
#pragma unroll
    for (int j = 0; j < 4; ++j) acc[i][j] = 0.f;

  const int srow = tid >> 2, kq = tid & 3;
  for (int k0 = 0; k0 < HIDN; k0 += 16) {
    {
      const float4 a4 = *reinterpret_cast<const float4*>(&A[(row0+srow)*HIDN + k0 + kq*4]);
      As[kq*4+0][srow] = a4.x; As[kq*4+1][srow] = a4.y;
      As[kq*4+2][srow] = a4.z; As[kq*4+3][srow] = a4.w;
      const float4 w4 = *reinterpret_cast<const float4*>(&W[(col0+srow)*HIDN + k0 + kq*4]);
      Bs[kq*4+0][srow] = w4.x; Bs[kq*4+1][srow] = w4.y;
      Bs[kq*4+2][srow] = w4.z; Bs[kq*4+3][srow] = w4.w;
    }
    __syncthreads();
#pragma unroll
    for (int kk = 0; kk < 16; ++kk) {
      const float4 av = *reinterpret_cast<const float4*>(&As[kk][ty*4]);
      const float4 bw = *reinterpret_cast<const float4*>(&Bs[kk][tx*4]);
      const float a_[4] = {av.x, av.y, av.z, av.w};
      const float b_[4] = {bw.x, bw.y, bw.z, bw.w};
#pragma unroll
      for (int i = 0; i < 4; ++i)
#pragma unroll
        for (int j = 0; j < 4; ++j)
          acc[i][j] = fmaf(a_[i], b_[j], acc[i][j]);
    }
    __syncthreads();
  }
  const int col = col0 + tx*4;
  const float4 b4 = *reinterpret_cast<const float4*>(&bias[col]);
  const int hh = col >> 6, d = col & 63;
#pragma unroll
  for (int i = 0; i < 4; ++i) {
    const int row = row0 + ty*4 + i;
    const int b = row >> 8, l = row & 255;
    float4 v;
    v.x = acc[i][0] + b4.x; v.y = acc[i][1] + b4.y;
    v.z = acc[i][2] + b4.z; v.w = acc[i][3] + b4.w;
    *reinterpret_cast<float4*>(&C[(((b*NHEAD + hh)*NL) + l)*DHEAD + d]) = v;
  }
}

// ---------------- v_frag: VH (head-major f32) -> bf16 MFMA B-fragments in ws ----------------
// element (k,d) -> tile=(k>>5)*4+(d>>4); lane=((k>>3)&3)*16+(d&15); j=k&7
__global__ __launch_bounds__(256) void v_frag(float* __restrict__ ws)
{
  const int bh = blockIdx.y;
  const int pair = blockIdx.x * 256 + threadIdx.x;   // 0..2047
  const int tile = pair >> 6;
  const int lane = pair & 63;
  const int base_k = (tile >> 2) * 32 + (lane >> 4) * 8;
  const int d = (tile & 3) * 16 + (lane & 15);
  const float* V = ws + WS_VH + (bh * NL) * DHEAD;
  short o[8];
#pragma unroll
  for (int j = 0; j < 8; ++j)
    o[j] = f2bf(V[(base_k + j) * DHEAD + d]);
  short* dst = reinterpret_cast<short*>(ws + WS_VF) + ((bh * 32 + tile) * 64 + lane) * 8;
  *reinterpret_cast<bf16x8*>(dst) = *reinterpret_cast<const bf16x8*>(o);
}

// ---------------- out GEMM: 64x32 tile ----------------
__global__ __launch_bounds__(256) void out_gemm(
    const float* __restrict__ A, const float* __restrict__ W,
    const float* __restrict__ bias, float* __restrict__ C)
{
  const int row0 = blockIdx.y * 64;
  const int col0 = blockIdx.x * 32;
  __shared__ float As[16][72];
  __shared__ float Bs[16][40];
  const int tid = threadIdx.x;
  const int tx = tid & 15;
  const int ty = tid >> 4;
  float acc00=0,acc01=0,acc10=0,acc11=0,acc20=0,acc21=0,acc30=0,acc31=0;

  for (int k0 = 0; k0 < HIDN; k0 += 16) {
    {
      const int arow = tid >> 2, kq = tid & 3;
      const float4 a4 = *reinterpret_cast<const float4*>(&A[(row0+arow)*HIDN + k0 + kq*4]);
      As[kq*4+0][arow] = a4.x; As[kq*4+1][arow] = a4.y;
      As[kq*4+2][arow] = a4.z; As[kq*4+3][arow] = a4.w;
    }
    if (tid < 128) {
      const int wcol = tid >> 2, kq = tid & 3;
      const float4 w4 = *reinterpret_cast<const float4*>(&W[(col0+wcol)*HIDN + k0 + kq*4]);
      Bs[kq*4+0][wcol] = w4.x; Bs[kq*4+1][wcol] = w4.y;
      Bs[kq*4+2][wcol] = w4.z; Bs[kq*4+3][wcol] = w4.w;
    }
    __syncthreads();
#pragma unroll
    for (int kk = 0; kk < 16; ++kk) {
      const float4 av  = *reinterpret_cast<const float4*>(&As[kk][ty*4]);
      const float2 bv2 = *reinterpret_cast<const float2*>(&Bs[kk][tx*2]);
      acc00 = fmaf(av.x, bv2.x, acc00);
      acc01 = fmaf(av.x, bv2.y, acc01);
      acc10 = fmaf(av.y, bv2.x, acc10);
      acc11 = fmaf(av.y, bv2.y, acc11);
      acc20 = fmaf(av.z, bv2.x, acc20);
      acc21 = fmaf(av.z, bv2.y, acc21);
      acc30 = fmaf(av.w, bv2.x, acc30);
      acc31 = fmaf(av.w, bv2.y, acc31);
    }
    __syncthreads();
  }
  const int c = col0 + tx*2;
  const float b0 = bias[c], b1v = bias[c+1];
  const float v0[4] = {acc00+b0, acc10+b0, acc20+b0, acc30+b0};
  const float v1[4] = {acc01+b1v, acc11+b1v, acc21+b1v, acc31+b1v};
#pragma unroll
  for (int i = 0; i < 4; ++i) {
    const int row = row0 + ty*4 + i;
    *reinterpret_cast<float2*>(&C[row*HIDN + c]) = make_float2(v0[i], v1[i]);
  }
}

// ---------------- attn: energy + (no-max) softmax + MFMA PV ----------------
// grid (16 qtiles, 32 bh), 512 threads. Thread (h=tid>>8, lk=tid&255) owns key lk
// for q-rows h*8..h*8+7. Rolling 8-wide d-window in registers (no kreg array!).
__global__ __launch_bounds__(512, 4) void attn_kernel(
    const float* __restrict__ ws, const float* __restrict__ va_w,
    float* __restrict__ attn_out, float* __restrict__ X)
{
  const int qt = blockIdx.x;
  const int bh = blockIdx.y;
  const int tid = threadIdx.x;

  __shared__ __align__(16) short aLb[8][64][8];      // 8 KB  P as bf16 A-fragments
  __shared__ __align__(16) float Qtl[16][64];        // 4 KB
  __shared__ __align__(16) float vaS[64];
  __shared__ __align__(16) float reds[2][4][8];

  const float* Qt  = ws + WS_QT + (bh*NL + qt*16)*DHEAD;
  const float* KtB = ws + WS_KT + bh*NL*DHEAD;
  const short* VF  = reinterpret_cast<const short*>(ws + WS_VF) + bh*32*64*8;

  if (tid < 256)
    reinterpret_cast<float4*>(Qtl)[tid] = reinterpret_cast<const float4*>(Qt)[tid];
  if (tid < 64) vaS[tid] = -2.0f * va_w[tid];

  const int h  = tid >> 8;
  const int lk = tid & 255;
  const int wv = lk >> 6;
  const int l  = lk & 63;
  const float* KtRow = KtB + lk*DHEAD;
  __syncthreads();

  float acc[8];
#pragma unroll
  for (int qi = 0; qi < 8; ++qi) acc[qi] = 0.f;

  // energy: rolling 8-d window; 64 evals per iteration. No register array for Kt.
#pragma unroll 1
  for (int d0 = 0; d0 < 64; d0 += 8) {
    const f32x4 ka = *reinterpret_cast<const f32x4*>(KtRow + d0);
    const f32x4 kb = *reinterpret_cast<const f32x4*>(KtRow + d0 + 4);
    const f32x4 vaA = *reinterpret_cast<const f32x4*>(&vaS[d0]);
    const f32x4 vaB = *reinterpret_cast<const f32x4*>(&vaS[d0 + 4]);
#pragma unroll
    for (int qi = 0; qi < 8; ++qi) {
      const f32x4 qa = *reinterpret_cast<const f32x4*>(&Qtl[h*8+qi][d0]);
      const f32x4 qb = *reinterpret_cast<const f32x4*>(&Qtl[h*8+qi][d0 + 4]);
      float a = acc[qi];
      a = fmaf(vaA.x, __builtin_amdgcn_rcpf(1.0f + __builtin_amdgcn_exp2f(qa.x + ka.x)), a);
      a = fmaf(vaA.y, __builtin_amdgcn_rcpf(1.0f + __builtin_amdgcn_exp2f(qa.y + ka.y)), a);
      a = fmaf(vaA.z, __builtin_amdgcn_rcpf(1.0f + __builtin_amdgcn_exp2f(qa.z + ka.z)), a);
      a = fmaf(vaA.w, __builtin_amdgcn_rcpf(1.0f + __builtin_amdgcn_exp2f(qa.w + ka.w)), a);
      a = fmaf(vaB.x, __builtin_amdgcn_rcpf(1.0f + __builtin_amdgcn_exp2f(qb.x + kb.x)), a);
      a = fmaf(vaB.y, __builtin_amdgcn_rcpf(1.0f + __builtin_amdgcn_exp2f(qb.y + kb.y)), a);
      a = fmaf(vaB.z, __builtin_amdgcn_rcpf(1.0f + __builtin_amdgcn_exp2f(qb.z + kb.z)), a);
      a = fmaf(vaB.w, __builtin_amdgcn_rcpf(1.0f + __builtin_amdgcn_exp2f(qb.w + kb.w)), a);
      acc[qi] = a;
    }
  }

  // p = exp(e) (|e| <= ~2*sum|va| ~ 8 -> no max shift needed)
  float p[8];
#pragma unroll
  for (int qi = 0; qi < 8; ++qi)
    p[qi] = __builtin_amdgcn_exp2f(acc[qi] * LOG2E);

#pragma unroll
  for (int qi = 0; qi < 8; ++qi) {
    float s = p[qi];
#pragma unroll
    for (int off = 1; off < 64; off <<= 1)
      s += __shfl_xor(s, off);
    if (l == 0) reds[h][wv][qi] = s;
  }
  // publish P as bf16 A-fragments
  {
    const int kb2 = lk >> 5;
    const int lbase = ((lk >> 3) & 3) * 16;
    const int jb = lk & 7;
#pragma unroll
    for (int qi = 0; qi < 8; ++qi)
      aLb[kb2][lbase + h*8 + qi][jb] = f2bf(p[qi]);
  }
  __syncthreads();

  // totals + attention output (f32 exact path)
  {
    f32x4 slo = {0.f,0.f,0.f,0.f}, shi = {0.f,0.f,0.f,0.f};
#pragma unroll
    for (int w2 = 0; w2 < 4; ++w2) {
      slo += *reinterpret_cast<const f32x4*>(&reds[h][w2][0]);
      shi += *reinterpret_cast<const f32x4*>(&reds[h][w2][4]);
    }
    float inv[8];
    inv[0] = __builtin_amdgcn_rcpf(slo.x); inv[1] = __builtin_amdgcn_rcpf(slo.y);
    inv[2] = __builtin_amdgcn_rcpf(slo.z); inv[3] = __builtin_amdgcn_rcpf(slo.w);
    inv[4] = __builtin_amdgcn_rcpf(shi.x); inv[5] = __builtin_amdgcn_rcpf(shi.y);
    inv[6] = __builtin_amdgcn_rcpf(shi.z); inv[7] = __builtin_amdgcn_rcpf(shi.w);
#pragma unroll
    for (int qi = 0; qi < 8; ++qi)
      attn_out[(bh*NL + qt*16 + h*8 + qi)*NL + lk] = p[qi] * inv[qi];

    // PV via MFMA: waves 0..3 (wid = d-block), V B-fragments straight from global (L2-hot)
    const int wid = tid >> 6;
    if (wid < 4) {
      f32x4 pacc = {0.f,0.f,0.f,0.f};
#pragma unroll
      for (int kb2 = 0; kb2 < 8; ++kb2) {
        const bf16x8 af  = *reinterpret_cast<const bf16x8*>(&aLb[kb2][l][0]);
        const bf16x8 bff = *reinterpret_cast<const bf16x8*>(&VF[((kb2*4 + wid)*64 + l)*8]);
        pacc = __builtin_amdgcn_mfma_f32_16x16x32_bf16(af, bff, pacc, 0, 0, 0);
      }
      const int b_ = bh >> 3, hh = bh & 7;
      const int colv = hh*DHEAD + wid*16 + (l & 15);
#pragma unroll
      for (int r = 0; r < 4; ++r) {
        const int row = (l >> 4)*4 + r;            // q index 0..15
        float stot = reds[row>>3][0][row&7] + reds[row>>3][1][row&7]
                   + reds[row>>3][2][row&7] + reds[row>>3][3][row&7];
        X[((b_*NL + qt*16 + row)*HIDN) + colv] = pacc[r] * __builtin_amdgcn_rcpf(stot);
      }
    }
  }
}

extern "C" void kernel_launch(void* const* d_in, const int* in_sizes, int n_in,
                              void* d_out, int out_size, void* d_ws, size_t ws_size,
                              hipStream_t stream) {
  const float* query = (const float*)d_in[0];
  const float* key   = (const float*)d_in[1];
  const float* value = (const float*)d_in[2];
  const float* Wq = (const float*)d_in[3];
  const float* bq = (const float*)d_in[4];
  const float* Wk = (const float*)d_in[5];
  const float* bk = (const float*)d_in[6];
  const float* Wv = (const float*)d_in[7];
  const float* bv = (const float*)d_in[8];
  const float* W1 = (const float*)d_in[9];
  const float* b1 = (const float*)d_in[10];
  const float* W2 = (const float*)d_in[11];
  const float* b2 = (const float*)d_in[12];
  const float* va_w = (const float*)d_in[13];
  const float* Wo = (const float*)d_in[15];
  const float* bo = (const float*)d_in[16];

  float* out = (float*)d_out;
  float* ws  = (float*)d_ws;
  float* attn = out + NROW*HIDN;   // output 1: attention [B,H,Lq,Lk]

  fuse_weights<<<dim3(4, 32, 2), 256, 0, stream>>>(Wq, bq, Wk, bk, W1, b1, W2, b2, ws);
  proj_gemm<<<dim3(8, 16, 3), 256, 0, stream>>>(query, key, value, Wv, bv, ws);
  v_frag<<<dim3(8, 32), 256, 0, stream>>>(ws);   // after proj (reads VH, overwrites dead WQF)
  attn_kernel<<<dim3(16, 32), 512, 0, stream>>>(ws, va_w, attn, ws + WS_X);
  out_gemm<<<dim3(16, 16), 256, 0, stream>>>(ws + WS_X, Wo, bo, out);
}

// Round 5
// 78.901 us; speedup vs baseline: 4.9722x; 1.4180x over previous
//
#include <hip/hip_runtime.h>

#define HIDN 512
#define NHEAD 8
#define DHEAD 64
#define NB 4
#define NL 256
#define NROW 1024   // NB*NL

// 2*log2(e): exp(2y) = exp2(y * SCALE2)
#define SCALE2 2.8853900817779268f
#define LOG2E  1.4426950408889634f

// workspace layout (float offsets) — total 2622464 floats (same as prior rounds)
#define WS_WQB 0                       // fused Wq'' bf16 [512][512]   (131072 floats)
#define WS_WKB (WS_WQB + 131072)       // fused Wk'' bf16
#define WS_BQF (WS_WKB + 131072)       // fused bq'' f32 [512]
#define WS_BKF (WS_BQF + 512)          // fused bk'' f32 [512]
#define WS_QBF (WS_BKF + 512)          // query bf16 [1024][512] (262144 fl); reused as X bf16 after proj
#define WS_KBF (WS_QBF + 262144)       // key bf16
#define WS_VBF (WS_KBF + 262144)       // value bf16
#define WS_WVB (WS_VBF + 262144)       // Wv bf16 [512][512]
#define WS_WOB (WS_WVB + 131072)       // Wo bf16 [512][512]
#define WS_QT  (WS_WOB + 131072)       // Qt f32 head-major [32bh][256][64]
#define WS_KT  (WS_QT + 524288)        // Kt f32 head-major
#define WS_VF  (WS_KT + 524288)        // V bf16 MFMA B-fragments [32bh][32tile][64lane][8j]

typedef __attribute__((ext_vector_type(4))) float f32x4;
typedef __attribute__((ext_vector_type(8))) short bf16x8;

__device__ __forceinline__ short f2bf(float x) {
  unsigned u = __float_as_uint(x);
  u += 0x7fffu + ((u >> 16) & 1u);   // RNE
  return (short)(u >> 16);
}

// ---------------- fuse_weights: fold W1/W2 (and SCALE2) into Wq/Wk -> bf16 ----------------
__global__ __launch_bounds__(256) void fuse_weights(
    const float* __restrict__ Wq, const float* __restrict__ bq,
    const float* __restrict__ Wk, const float* __restrict__ bk,
    const float* __restrict__ W1, const float* __restrict__ b1,
    const float* __restrict__ W2, const float* __restrict__ b2,
    float* __restrict__ ws)
{
  const int h  = blockIdx.y >> 2;
  const int ig = blockIdx.y & 3;       // 16-row group within head
  const int c0 = blockIdx.x * 128;
  const int which = blockIdx.z;
  const float* Wsrc = which ? Wk : Wq;
  const float* bsrc = which ? bk : bq;
  const float* Wt   = which ? W2 : W1;
  const float* bt   = which ? b2 : b1;
  short* Wout = reinterpret_cast<short*>(ws + (which ? WS_WKB : WS_WQB));
  float* bout = ws + (which ? WS_BKF : WS_BQF);

  __shared__ float Wtl[16][68];
  for (int t = threadIdx.x; t < 16*64; t += 256)
    Wtl[t >> 6][t & 63] = Wt[(ig*16 + (t >> 6))*64 + (t & 63)];
  __syncthreads();

  const int c  = c0 + (threadIdx.x & 127);
  const int i0 = (threadIdx.x >> 7) * 8;   // local row base (0 or 8)
  float acc[8];
#pragma unroll
  for (int ii = 0; ii < 8; ++ii) acc[ii] = 0.f;

  for (int j0 = 0; j0 < 64; j0 += 4) {
    const float s0 = Wsrc[(h*64 + j0 + 0)*HIDN + c];
    const float s1 = Wsrc[(h*64 + j0 + 1)*HIDN + c];
    const float s2 = Wsrc[(h*64 + j0 + 2)*HIDN + c];
    const float s3 = Wsrc[(h*64 + j0 + 3)*HIDN + c];
#pragma unroll
    for (int ii = 0; ii < 8; ++ii) {
      const float4 wv = *reinterpret_cast<const float4*>(&Wtl[i0+ii][j0]);
      float a = acc[ii];
      a = fmaf(wv.x, s0, a);
      a = fmaf(wv.y, s1, a);
      a = fmaf(wv.z, s2, a);
      a = fmaf(wv.w, s3, a);
      acc[ii] = a;
    }
  }
#pragma unroll
  for (int ii = 0; ii < 8; ++ii)
    Wout[(h*64 + ig*16 + i0 + ii)*HIDN + c] = f2bf(acc[ii] * SCALE2);

  if (blockIdx.x == 0 && threadIdx.x < 16) {
    const int il = threadIdx.x;
    float a = bt[ig*16 + il];
    for (int j = 0; j < 64; ++j)
      a = fmaf(Wtl[il][j], bsrc[h*64 + j], a);
    bout[h*64 + ig*16 + il] = a * SCALE2;
  }
}

// ---------------- to_bf16: q/k/v/Wv/Wo f32 -> bf16 row-major copies ----------------
__global__ __launch_bounds__(256) void to_bf16(
    const float* __restrict__ q, const float* __restrict__ k, const float* __restrict__ v,
    const float* __restrict__ Wv, const float* __restrict__ Wo, float* __restrict__ ws)
{
  const int z = blockIdx.z;
  const float* src; short* dst; int n;
  if (z == 0)      { src = q;  dst = (short*)(ws + WS_QBF); n = 524288; }
  else if (z == 1) { src = k;  dst = (short*)(ws + WS_KBF); n = 524288; }
  else if (z == 2) { src = v;  dst = (short*)(ws + WS_VBF); n = 524288; }
  else if (z == 3) { src = Wv; dst = (short*)(ws + WS_WVB); n = 262144; }
  else             { src = Wo; dst = (short*)(ws + WS_WOB); n = 262144; }
  const int i = (blockIdx.x * 256 + threadIdx.x) * 8;
  if (i >= n) return;
  const float4 a = *reinterpret_cast<const float4*>(src + i);
  const float4 b = *reinterpret_cast<const float4*>(src + i + 4);
  bf16x8 o;
  o[0] = f2bf(a.x); o[1] = f2bf(a.y); o[2] = f2bf(a.z); o[3] = f2bf(a.w);
  o[4] = f2bf(b.x); o[5] = f2bf(b.y); o[6] = f2bf(b.z); o[7] = f2bf(b.w);
  *reinterpret_cast<bf16x8*>(dst + i) = o;
}

// ---------------- mfma_proj: C = A(bf16) @ W(bf16)^T + bias ----------------
// LDS-free: fragments loaded directly from row-major global (L2-resident).
// Wave = 16 rows x 64 cols; block = 4 waves stacked in M. Grid (8 ncol, 16 mrow, 3 z).
// z=0 -> QT f32 head-major; z=1 -> KT f32 head-major; z=2 -> VF bf16 fragments.
__global__ __launch_bounds__(256) void mfma_proj(float* __restrict__ ws, const float* __restrict__ bv)
{
  const int z = blockIdx.z;
  const short* A; const short* W; const float* bias;
  if (z == 0)      { A = (const short*)(ws + WS_QBF); W = (const short*)(ws + WS_WQB); bias = ws + WS_BQF; }
  else if (z == 1) { A = (const short*)(ws + WS_KBF); W = (const short*)(ws + WS_WKB); bias = ws + WS_BKF; }
  else             { A = (const short*)(ws + WS_VBF); W = (const short*)(ws + WS_WVB); bias = bv; }

  const int wid  = threadIdx.x >> 6;
  const int lane = threadIdx.x & 63;
  const int mt = blockIdx.y * 4 + wid;     // m-tile 0..63
  const int nb = blockIdx.x * 64;          // n base
  const short* aptr = A + (mt*16 + (lane & 15))*HIDN + (lane >> 4)*8;
  const short* wptr = W + (nb + (lane & 15))*HIDN + (lane >> 4)*8;

  f32x4 acc[4] = {{0,0,0,0},{0,0,0,0},{0,0,0,0},{0,0,0,0}};
#pragma unroll 4
  for (int k0 = 0; k0 < HIDN; k0 += 32) {
    const bf16x8 af = *reinterpret_cast<const bf16x8*>(aptr + k0);
    const short* wp = wptr + k0;
#pragma unroll
    for (int t = 0; t < 4; ++t)
      acc[t] = __builtin_amdgcn_mfma_f32_16x16x32_bf16(
          af, *reinterpret_cast<const bf16x8*>(wp + t*16*HIDN), acc[t], 0, 0, 0);
  }

  const int rbase = mt*16 + (lane >> 4)*4;
  if (z < 2) {
    float* dst = ws + (z == 0 ? WS_QT : WS_KT);
#pragma unroll
    for (int t = 0; t < 4; ++t) {
      const int c = nb + t*16 + (lane & 15);
      const float bc = bias[c];
      const int hh = c >> 6, d = c & 63;
#pragma unroll
      for (int r = 0; r < 4; ++r) {
        const int R = rbase + r;
        dst[(((R >> 8)*NHEAD + hh)*NL + (R & 255))*DHEAD + d] = acc[t][r] + bc;
      }
    }
  } else {
    short* vf = reinterpret_cast<short*>(ws + WS_VF);
#pragma unroll
    for (int t = 0; t < 4; ++t) {
      const int c = nb + t*16 + (lane & 15);
      const float bc = bias[c];
      const int hh = c >> 6, d = c & 63;
#pragma unroll
      for (int r = 0; r < 4; ++r) {
        const int R = rbase + r;
        const int l = R & 255;
        const int bh = (R >> 8)*NHEAD + hh;
        const int tile = ((l >> 5) << 2) + (d >> 4);
        const int lanep = (((l >> 3) & 3) << 4) + (d & 15);
        vf[((bh*32 + tile)*64 + lanep)*8 + (l & 7)] = f2bf(acc[t][r] + bc);
      }
    }
  }
}

// ---------------- mfma_out: out = X(bf16) @ Wo(bf16)^T + bo, f32 row-major ----------------
__global__ __launch_bounds__(256) void mfma_out(
    float* __restrict__ ws, const float* __restrict__ bo, float* __restrict__ out)
{
  const short* A = (const short*)(ws + WS_QBF);   // X bf16 (reused region)
  const short* W = (const short*)(ws + WS_WOB);
  const int wid  = threadIdx.x >> 6;
  const int lane = threadIdx.x & 63;
  const int mt = blockIdx.y * 4 + wid;
  const int nb = blockIdx.x * 64;
  const short* aptr = A + (mt*16 + (lane & 15))*HIDN + (lane >> 4)*8;
  const short* wptr = W + (nb + (lane & 15))*HIDN + (lane >> 4)*8;

  f32x4 acc[4] = {{0,0,0,0},{0,0,0,0},{0,0,0,0},{0,0,0,0}};
#pragma unroll 4
  for (int k0 = 0; k0 < HIDN; k0 += 32) {
    const bf16x8 af = *reinterpret_cast<const bf16x8*>(aptr + k0);
    const short* wp = wptr + k0;
#pragma unroll
    for (int t = 0; t < 4; ++t)
      acc[t] = __builtin_amdgcn_mfma_f32_16x16x32_bf16(
          af, *reinterpret_cast<const bf16x8*>(wp + t*16*HIDN), acc[t], 0, 0, 0);
  }

  const int rbase = mt*16 + (lane >> 4)*4;
#pragma unroll
  for (int t = 0; t < 4; ++t) {
    const int c = nb + t*16 + (lane & 15);
    const float bc = bo[c];
#pragma unroll
    for (int r = 0; r < 4; ++r)
      out[(rbase + r)*HIDN + c] = acc[t][r] + bc;
  }
}

// ---------------- attn: energy + (no-max) softmax + MFMA PV ----------------
// grid (16 qtiles, 32 bh), 512 threads. Thread (h=tid>>8, lk=tid&255) owns key lk
// for q-rows h*8..h*8+7. Rolling 8-wide d-window in registers (no kreg array).
__global__ __launch_bounds__(512, 4) void attn_kernel(
    float* __restrict__ ws, const float* __restrict__ va_w,
    float* __restrict__ attn_out)
{
  const int qt = blockIdx.x;
  const int bh = blockIdx.y;
  const int tid = threadIdx.x;

  __shared__ __align__(16) short aLb[8][64][8];      // 8 KB  P as bf16 A-fragments
  __shared__ __align__(16) float Qtl[16][64];        // 4 KB
  __shared__ __align__(16) float vaS[64];
  __shared__ __align__(16) float reds[2][4][8];

  const float* Qt  = ws + WS_QT + (bh*NL + qt*16)*DHEAD;
  const float* KtB = ws + WS_KT + bh*NL*DHEAD;
  const short* VF  = reinterpret_cast<const short*>(ws + WS_VF) + bh*32*64*8;
  short* Xb = reinterpret_cast<short*>(ws + WS_QBF);

  if (tid < 256)
    reinterpret_cast<float4*>(Qtl)[tid] = reinterpret_cast<const float4*>(Qt)[tid];
  if (tid < 64) vaS[tid] = -2.0f * va_w[tid];

  const int h  = tid >> 8;
  const int lk = tid & 255;
  const int wv = lk >> 6;
  const int l  = lk & 63;
  const float* KtRow = KtB + lk*DHEAD;
  __syncthreads();

  float acc[8];
#pragma unroll
  for (int qi = 0; qi < 8; ++qi) acc[qi] = 0.f;

#pragma unroll 1
  for (int d0 = 0; d0 < 64; d0 += 8) {
    const f32x4 ka = *reinterpret_cast<const f32x4*>(KtRow + d0);
    const f32x4 kb = *reinterpret_cast<const f32x4*>(KtRow + d0 + 4);
    const f32x4 vaA = *reinterpret_cast<const f32x4*>(&vaS[d0]);
    const f32x4 vaB = *reinterpret_cast<const f32x4*>(&vaS[d0 + 4]);
#pragma unroll
    for (int qi = 0; qi < 8; ++qi) {
      const f32x4 qa = *reinterpret_cast<const f32x4*>(&Qtl[h*8+qi][d0]);
      const f32x4 qb = *reinterpret_cast<const f32x4*>(&Qtl[h*8+qi][d0 + 4]);
      float a = acc[qi];
      a = fmaf(vaA.x, __builtin_amdgcn_rcpf(1.0f + __builtin_amdgcn_exp2f(qa.x + ka.x)), a);
      a = fmaf(vaA.y, __builtin_amdgcn_rcpf(1.0f + __builtin_amdgcn_exp2f(qa.y + ka.y)), a);
      a = fmaf(vaA.z, __builtin_amdgcn_rcpf(1.0f + __builtin_amdgcn_exp2f(qa.z + ka.z)), a);
      a = fmaf(vaA.w, __builtin_amdgcn_rcpf(1.0f + __builtin_amdgcn_exp2f(qa.w + ka.w)), a);
      a = fmaf(vaB.x, __builtin_amdgcn_rcpf(1.0f + __builtin_amdgcn_exp2f(qb.x + kb.x)), a);
      a = fmaf(vaB.y, __builtin_amdgcn_rcpf(1.0f + __builtin_amdgcn_exp2f(qb.y + kb.y)), a);
      a = fmaf(vaB.z, __builtin_amdgcn_rcpf(1.0f + __builtin_amdgcn_exp2f(qb.z + kb.z)), a);
      a = fmaf(vaB.w, __builtin_amdgcn_rcpf(1.0f + __builtin_amdgcn_exp2f(qb.w + kb.w)), a);
      acc[qi] = a;
    }
  }

  // p = exp(e) (|e| <= ~2*sum|va| ~ 8 -> no max shift needed)
  float p[8];
#pragma unroll
  for (int qi = 0; qi < 8; ++qi)
    p[qi] = __builtin_amdgcn_exp2f(acc[qi] * LOG2E);

#pragma unroll
  for (int qi = 0; qi < 8; ++qi) {
    float s = p[qi];
#pragma unroll
    for (int off = 1; off < 64; off <<= 1)
      s += __shfl_xor(s, off);
    if (l == 0) reds[h][wv][qi] = s;
  }
  // publish P as bf16 A-fragments
  {
    const int kb2 = lk >> 5;
    const int lbase = ((lk >> 3) & 3) * 16;
    const int jb = lk & 7;
#pragma unroll
    for (int qi = 0; qi < 8; ++qi)
      aLb[kb2][lbase + h*8 + qi][jb] = f2bf(p[qi]);
  }
  __syncthreads();

  {
    f32x4 slo = {0.f,0.f,0.f,0.f}, shi = {0.f,0.f,0.f,0.f};
#pragma unroll
    for (int w2 = 0; w2 < 4; ++w2) {
      slo += *reinterpret_cast<const f32x4*>(&reds[h][w2][0]);
      shi += *reinterpret_cast<const f32x4*>(&reds[h][w2][4]);
    }
    float inv[8];
    inv[0] = __builtin_amdgcn_rcpf(slo.x); inv[1] = __builtin_amdgcn_rcpf(slo.y);
    inv[2] = __builtin_amdgcn_rcpf(slo.z); inv[3] = __builtin_amdgcn_rcpf(slo.w);
    inv[4] = __builtin_amdgcn_rcpf(shi.x); inv[5] = __builtin_amdgcn_rcpf(shi.y);
    inv[6] = __builtin_amdgcn_rcpf(shi.z); inv[7] = __builtin_amdgcn_rcpf(shi.w);
#pragma unroll
    for (int qi = 0; qi < 8; ++qi)
      attn_out[(bh*NL + qt*16 + h*8 + qi)*NL + lk] = p[qi] * inv[qi];

    // PV via MFMA: waves 0..3 (wid = d-block), V B-fragments straight from global (L2-hot)
    const int wid = tid >> 6;
    if (wid < 4) {
      f32x4 pacc = {0.f,0.f,0.f,0.f};
#pragma unroll
      for (int kb2 = 0; kb2 < 8; ++kb2) {
        const bf16x8 af  = *reinterpret_cast<const bf16x8*>(&aLb[kb2][l][0]);
        const bf16x8 bff = *reinterpret_cast<const bf16x8*>(&VF[((kb2*4 + wid)*64 + l)*8]);
        pacc = __builtin_amdgcn_mfma_f32_16x16x32_bf16(af, bff, pacc, 0, 0, 0);
      }
      const int b_ = bh >> 3, hh = bh & 7;
      const int colv = hh*DHEAD + wid*16 + (l & 15);
#pragma unroll
      for (int r = 0; r < 4; ++r) {
        const int row = (l >> 4)*4 + r;            // q index 0..15
        float stot = reds[row>>3][0][row&7] + reds[row>>3][1][row&7]
                   + reds[row>>3][2][row&7] + reds[row>>3][3][row&7];
        Xb[(b_*NL + qt*16 + row)*HIDN + colv] = f2bf(pacc[r] * __builtin_amdgcn_rcpf(stot));
      }
    }
  }
}

extern "C" void kernel_launch(void* const* d_in, const int* in_sizes, int n_in,
                              void* d_out, int out_size, void* d_ws, size_t ws_size,
                              hipStream_t stream) {
  const float* query = (const float*)d_in[0];
  const float* key   = (const float*)d_in[1];
  const float* value = (const float*)d_in[2];
  const float* Wq = (const float*)d_in[3];
  const float* bq = (const float*)d_in[4];
  const float* Wk = (const float*)d_in[5];
  const float* bk = (const float*)d_in[6];
  const float* Wv = (const float*)d_in[7];
  const float* bv = (const float*)d_in[8];
  const float* W1 = (const float*)d_in[9];
  const float* b1 = (const float*)d_in[10];
  const float* W2 = (const float*)d_in[11];
  const float* b2 = (const float*)d_in[12];
  const float* va_w = (const float*)d_in[13];
  const float* Wo = (const float*)d_in[15];
  const float* bo = (const float*)d_in[16];

  float* out = (float*)d_out;
  float* ws  = (float*)d_ws;
  float* attn = out + NROW*HIDN;   // output 1: attention [B,H,Lq,Lk]

  fuse_weights<<<dim3(4, 32, 2), 256, 0, stream>>>(Wq, bq, Wk, bk, W1, b1, W2, b2, ws);
  to_bf16<<<dim3(256, 1, 5), 256, 0, stream>>>(query, key, value, Wv, Wo, ws);
  mfma_proj<<<dim3(8, 16, 3), 256, 0, stream>>>(ws, bv);
  attn_kernel<<<dim3(16, 32), 512, 0, stream>>>(ws, va_w, attn);
  mfma_out<<<dim3(8, 16), 256, 0, stream>>>(ws, bo, out);
}

// Round 6
// 74.439 us; speedup vs baseline: 5.2702x; 1.0599x over previous
//
#include <hip/hip_runtime.h>

#define HIDN 512
#define NHEAD 8
#define DHEAD 64
#define NB 4
#define NL 256
#define NROW 1024   // NB*NL

// 2*log2(e): exp(2y) = exp2(y * SCALE2)
#define SCALE2 2.8853900817779268f
#define LOG2E  1.4426950408889634f

// workspace layout (float offsets)
#define WS_WQB 0                       // fused Wq'' bf16 [512][512]   (131072 floats)
#define WS_WKB (WS_WQB + 131072)       // fused Wk'' bf16
#define WS_BQF (WS_WKB + 131072)       // fused bq'' f32 [512]
#define WS_BKF (WS_BQF + 512)          // fused bk'' f32 [512]
#define WS_QBF (WS_BKF + 512)          // query bf16 [1024][512]; reused as X bf16 after proj
#define WS_KBF (WS_QBF + 262144)       // key bf16
#define WS_VBF (WS_KBF + 262144)       // value bf16
#define WS_WVB (WS_VBF + 262144)       // Wv bf16 [512][512]
#define WS_WOB (WS_WVB + 131072)       // Wo bf16 [512][512]
#define WS_QT  (WS_WOB + 131072)       // Qt f32 head-major [32bh][256][64]
#define WS_KT  (WS_QT + 524288)        // Kt f32 head-major
#define WS_VF  (WS_KT + 524288)        // V bf16 MFMA B-fragments [32bh][32tile][64lane][8j]

typedef __attribute__((ext_vector_type(4))) float f32x4;
typedef __attribute__((ext_vector_type(8))) short bf16x8;

__device__ __forceinline__ short f2bf(float x) {
  unsigned u = __float_as_uint(x);
  u += 0x7fffu + ((u >> 16) & 1u);   // RNE
  return (short)(u >> 16);
}

// ---------------- prep: z=0/1 fold W1/W2 (+SCALE2) into Wq/Wk -> bf16; z=2..6 f32->bf16 copies
__global__ __launch_bounds__(256) void prep(
    const float* __restrict__ Wq, const float* __restrict__ bq,
    const float* __restrict__ Wk, const float* __restrict__ bk,
    const float* __restrict__ W1, const float* __restrict__ b1,
    const float* __restrict__ W2, const float* __restrict__ b2,
    const float* __restrict__ q, const float* __restrict__ k, const float* __restrict__ v,
    const float* __restrict__ Wv, const float* __restrict__ Wo,
    float* __restrict__ ws)
{
  const int z = blockIdx.z;
  if (z >= 2) {
    const int zz = z - 2;
    const float* src; short* dst; int n;
    if (zz == 0)      { src = q;  dst = (short*)(ws + WS_QBF); n = 524288; }
    else if (zz == 1) { src = k;  dst = (short*)(ws + WS_KBF); n = 524288; }
    else if (zz == 2) { src = v;  dst = (short*)(ws + WS_VBF); n = 524288; }
    else if (zz == 3) { src = Wv; dst = (short*)(ws + WS_WVB); n = 262144; }
    else              { src = Wo; dst = (short*)(ws + WS_WOB); n = 262144; }
    const int i = (blockIdx.x * 256 + threadIdx.x) * 8;
    if (i >= n) return;
    const float4 a = *reinterpret_cast<const float4*>(src + i);
    const float4 b = *reinterpret_cast<const float4*>(src + i + 4);
    bf16x8 o;
    o[0] = f2bf(a.x); o[1] = f2bf(a.y); o[2] = f2bf(a.z); o[3] = f2bf(a.w);
    o[4] = f2bf(b.x); o[5] = f2bf(b.y); o[6] = f2bf(b.z); o[7] = f2bf(b.w);
    *reinterpret_cast<bf16x8*>(dst + i) = o;
    return;
  }

  if (blockIdx.x >= 128) return;
  const int c0 = (blockIdx.x & 3) * 128;
  const int y  = blockIdx.x >> 2;
  const int h  = y >> 2;
  const int ig = y & 3;                // 16-row group within head
  const int which = z;
  const float* Wsrc = which ? Wk : Wq;
  const float* bsrc = which ? bk : bq;
  const float* Wt   = which ? W2 : W1;
  const float* bt   = which ? b2 : b1;
  short* Wout = reinterpret_cast<short*>(ws + (which ? WS_WKB : WS_WQB));
  float* bout = ws + (which ? WS_BKF : WS_BQF);

  __shared__ float Wtl[16][68];
  for (int t = threadIdx.x; t < 16*64; t += 256)
    Wtl[t >> 6][t & 63] = Wt[(ig*16 + (t >> 6))*64 + (t & 63)];
  __syncthreads();

  const int c  = c0 + (threadIdx.x & 127);
  const int i0 = (threadIdx.x >> 7) * 8;   // local row base (0 or 8)
  float acc[8];
#pragma unroll
  for (int ii = 0; ii < 8; ++ii) acc[ii] = 0.f;

  for (int j0 = 0; j0 < 64; j0 += 4) {
    const float s0 = Wsrc[(h*64 + j0 + 0)*HIDN + c];
    const float s1 = Wsrc[(h*64 + j0 + 1)*HIDN + c];
    const float s2 = Wsrc[(h*64 + j0 + 2)*HIDN + c];
    const float s3 = Wsrc[(h*64 + j0 + 3)*HIDN + c];
#pragma unroll
    for (int ii = 0; ii < 8; ++ii) {
      const float4 wv4 = *reinterpret_cast<const float4*>(&Wtl[i0+ii][j0]);
      float a = acc[ii];
      a = fmaf(wv4.x, s0, a);
      a = fmaf(wv4.y, s1, a);
      a = fmaf(wv4.z, s2, a);
      a = fmaf(wv4.w, s3, a);
      acc[ii] = a;
    }
  }
#pragma unroll
  for (int ii = 0; ii < 8; ++ii)
    Wout[(h*64 + ig*16 + i0 + ii)*HIDN + c] = f2bf(acc[ii] * SCALE2);

  if (blockIdx.x == 0 && threadIdx.x < 16) {
    const int il = threadIdx.x;
    float a = bt[ig*16 + il];
    for (int j = 0; j < 64; ++j)
      a = fmaf(Wtl[il][j], bsrc[h*64 + j], a);
    bout[h*64 + ig*16 + il] = a * SCALE2;
  }
}

// ---------------- mfma_proj: C = A(bf16) @ W(bf16)^T + bias ----------------
// LDS-free: fragments loaded directly from row-major global (L2-resident).
__global__ __launch_bounds__(256) void mfma_proj(float* __restrict__ ws, const float* __restrict__ bv)
{
  const int z = blockIdx.z;
  const short* A; const short* W; const float* bias;
  if (z == 0)      { A = (const short*)(ws + WS_QBF); W = (const short*)(ws + WS_WQB); bias = ws + WS_BQF; }
  else if (z == 1) { A = (const short*)(ws + WS_KBF); W = (const short*)(ws + WS_WKB); bias = ws + WS_BKF; }
  else             { A = (const short*)(ws + WS_VBF); W = (const short*)(ws + WS_WVB); bias = bv; }

  const int wid  = threadIdx.x >> 6;
  const int lane = threadIdx.x & 63;
  const int mt = blockIdx.y * 4 + wid;     // m-tile 0..63
  const int nb = blockIdx.x * 64;          // n base
  const short* aptr = A + (mt*16 + (lane & 15))*HIDN + (lane >> 4)*8;
  const short* wptr = W + (nb + (lane & 15))*HIDN + (lane >> 4)*8;

  f32x4 acc[4] = {{0,0,0,0},{0,0,0,0},{0,0,0,0},{0,0,0,0}};
#pragma unroll 4
  for (int k0 = 0; k0 < HIDN; k0 += 32) {
    const bf16x8 af = *reinterpret_cast<const bf16x8*>(aptr + k0);
    const short* wp = wptr + k0;
#pragma unroll
    for (int t = 0; t < 4; ++t)
      acc[t] = __builtin_amdgcn_mfma_f32_16x16x32_bf16(
          af, *reinterpret_cast<const bf16x8*>(wp + t*16*HIDN), acc[t], 0, 0, 0);
  }

  const int rbase = mt*16 + (lane >> 4)*4;
  if (z < 2) {
    float* dst = ws + (z == 0 ? WS_QT : WS_KT);
#pragma unroll
    for (int t = 0; t < 4; ++t) {
      const int c = nb + t*16 + (lane & 15);
      const float bc = bias[c];
      const int hh = c >> 6, d = c & 63;
#pragma unroll
      for (int r = 0; r < 4; ++r) {
        const int R = rbase + r;
        dst[(((R >> 8)*NHEAD + hh)*NL + (R & 255))*DHEAD + d] = acc[t][r] + bc;
      }
    }
  } else {
    short* vf = reinterpret_cast<short*>(ws + WS_VF);
#pragma unroll
    for (int t = 0; t < 4; ++t) {
      const int c = nb + t*16 + (lane & 15);
      const float bc = bias[c];
      const int hh = c >> 6, d = c & 63;
#pragma unroll
      for (int r = 0; r < 4; ++r) {
        const int R = rbase + r;
        const int l = R & 255;
        const int bh = (R >> 8)*NHEAD + hh;
        const int tile = ((l >> 5) << 2) + (d >> 4);
        const int lanep = (((l >> 3) & 3) << 4) + (d & 15);
        vf[((bh*32 + tile)*64 + lanep)*8 + (l & 7)] = f2bf(acc[t][r] + bc);
      }
    }
  }
}

// ---------------- mfma_out: out = X(bf16) @ Wo(bf16)^T + bo, f32 row-major ----------------
__global__ __launch_bounds__(256) void mfma_out(
    float* __restrict__ ws, const float* __restrict__ bo, float* __restrict__ out)
{
  const short* A = (const short*)(ws + WS_QBF);   // X bf16 (reused region)
  const short* W = (const short*)(ws + WS_WOB);
  const int wid  = threadIdx.x >> 6;
  const int lane = threadIdx.x & 63;
  const int mt = blockIdx.y * 4 + wid;
  const int nb = blockIdx.x * 64;
  const short* aptr = A + (mt*16 + (lane & 15))*HIDN + (lane >> 4)*8;
  const short* wptr = W + (nb + (lane & 15))*HIDN + (lane >> 4)*8;

  f32x4 acc[4] = {{0,0,0,0},{0,0,0,0},{0,0,0,0},{0,0,0,0}};
#pragma unroll 4
  for (int k0 = 0; k0 < HIDN; k0 += 32) {
    const bf16x8 af = *reinterpret_cast<const bf16x8*>(aptr + k0);
    const short* wp = wptr + k0;
#pragma unroll
    for (int t = 0; t < 4; ++t)
      acc[t] = __builtin_amdgcn_mfma_f32_16x16x32_bf16(
          af, *reinterpret_cast<const bf16x8*>(wp + t*16*HIDN), acc[t], 0, 0, 0);
  }

  const int rbase = mt*16 + (lane >> 4)*4;
#pragma unroll
  for (int t = 0; t < 4; ++t) {
    const int c = nb + t*16 + (lane & 15);
    const float bc = bo[c];
#pragma unroll
    for (int r = 0; r < 4; ++r)
      out[(rbase + r)*HIDN + c] = acc[t][r] + bc;
  }
}

// ---------------- attn: energy + (no-max) softmax + MFMA PV ----------------
// grid (16 qtiles, 32 bh), 1024 threads (16 waves -> 2 blocks/CU = 8 waves/SIMD).
// Thread group g=tid>>8 owns q-rows g*4..g*4+3; thread lk=tid&255 owns key lk.
__global__ __launch_bounds__(1024, 8) void attn_kernel(
    float* __restrict__ ws, const float* __restrict__ va_w,
    float* __restrict__ attn_out)
{
  const int qt = blockIdx.x;
  const int bh = blockIdx.y;
  const int tid = threadIdx.x;

  __shared__ __align__(16) short aLb[8][64][8];      // 8 KB  P as bf16 A-fragments
  __shared__ __align__(16) float Qtl[16][64];        // 4 KB
  __shared__ __align__(16) float vaS[64];
  __shared__ __align__(16) float reds[4][4][4];      // [qgroup][wave][qi]

  const float* Qt  = ws + WS_QT + (bh*NL + qt*16)*DHEAD;
  const float* KtB = ws + WS_KT + bh*NL*DHEAD;
  const short* VF  = reinterpret_cast<const short*>(ws + WS_VF) + bh*32*64*8;
  short* Xb = reinterpret_cast<short*>(ws + WS_QBF);

  if (tid < 256)
    reinterpret_cast<float4*>(Qtl)[tid] = reinterpret_cast<const float4*>(Qt)[tid];
  if (tid >= 1024-64) vaS[tid & 63] = -2.0f * va_w[tid & 63];

  const int g  = tid >> 8;        // q-group: rows g*4 .. g*4+3
  const int lk = tid & 255;
  const int wv = lk >> 6;
  const int l  = lk & 63;
  const float* KtRow = KtB + lk*DHEAD;
  __syncthreads();

  float acc[4];
#pragma unroll
  for (int qi = 0; qi < 4; ++qi) acc[qi] = 0.f;

#pragma unroll 1
  for (int d0 = 0; d0 < 64; d0 += 8) {
    const f32x4 ka = *reinterpret_cast<const f32x4*>(KtRow + d0);
    const f32x4 kb = *reinterpret_cast<const f32x4*>(KtRow + d0 + 4);
    const f32x4 vaA = *reinterpret_cast<const f32x4*>(&vaS[d0]);
    const f32x4 vaB = *reinterpret_cast<const f32x4*>(&vaS[d0 + 4]);
#pragma unroll
    for (int qi = 0; qi < 4; ++qi) {
      const f32x4 qa = *reinterpret_cast<const f32x4*>(&Qtl[g*4+qi][d0]);
      const f32x4 qb = *reinterpret_cast<const f32x4*>(&Qtl[g*4+qi][d0 + 4]);
      float a = acc[qi];
      a = fmaf(vaA.x, __builtin_amdgcn_rcpf(1.0f + __builtin_amdgcn_exp2f(qa.x + ka.x)), a);
      a = fmaf(vaA.y, __builtin_amdgcn_rcpf(1.0f + __builtin_amdgcn_exp2f(qa.y + ka.y)), a);
      a = fmaf(vaA.z, __builtin_amdgcn_rcpf(1.0f + __builtin_amdgcn_exp2f(qa.z + ka.z)), a);
      a = fmaf(vaA.w, __builtin_amdgcn_rcpf(1.0f + __builtin_amdgcn_exp2f(qa.w + ka.w)), a);
      a = fmaf(vaB.x, __builtin_amdgcn_rcpf(1.0f + __builtin_amdgcn_exp2f(qb.x + kb.x)), a);
      a = fmaf(vaB.y, __builtin_amdgcn_rcpf(1.0f + __builtin_amdgcn_exp2f(qb.y + kb.y)), a);
      a = fmaf(vaB.z, __builtin_amdgcn_rcpf(1.0f + __builtin_amdgcn_exp2f(qb.z + kb.z)), a);
      a = fmaf(vaB.w, __builtin_amdgcn_rcpf(1.0f + __builtin_amdgcn_exp2f(qb.w + kb.w)), a);
      acc[qi] = a;
    }
  }

  // p = exp(e)  (|e| <= ~2*sum|va| ~ 8 -> no max shift needed)
  float p[4];
#pragma unroll
  for (int qi = 0; qi < 4; ++qi)
    p[qi] = __builtin_amdgcn_exp2f(acc[qi] * LOG2E);

#pragma unroll
  for (int qi = 0; qi < 4; ++qi) {
    float s = p[qi];
#pragma unroll
    for (int off = 1; off < 64; off <<= 1)
      s += __shfl_xor(s, off);
    if (l == 0) reds[g][wv][qi] = s;
  }
  // publish P as bf16 A-fragments
  {
    const int kb2 = lk >> 5;
    const int lbase = ((lk >> 3) & 3) * 16;
    const int jb = lk & 7;
#pragma unroll
    for (int qi = 0; qi < 4; ++qi)
      aLb[kb2][lbase + g*4 + qi][jb] = f2bf(p[qi]);
  }
  __syncthreads();

  // totals + attention output
  {
    f32x4 s4 = {0.f,0.f,0.f,0.f};
#pragma unroll
    for (int w2 = 0; w2 < 4; ++w2)
      s4 += *reinterpret_cast<const f32x4*>(&reds[g][w2][0]);
    float inv[4];
    inv[0] = __builtin_amdgcn_rcpf(s4.x); inv[1] = __builtin_amdgcn_rcpf(s4.y);
    inv[2] = __builtin_amdgcn_rcpf(s4.z); inv[3] = __builtin_amdgcn_rcpf(s4.w);
#pragma unroll
    for (int qi = 0; qi < 4; ++qi)
      attn_out[(bh*NL + qt*16 + g*4 + qi)*NL + lk] = p[qi] * inv[qi];

    // PV via MFMA: waves 0..3 (wid = d-block), V B-fragments from global (L2-hot)
    const int wid = tid >> 6;
    if (wid < 4) {
      f32x4 pacc = {0.f,0.f,0.f,0.f};
#pragma unroll
      for (int kb2 = 0; kb2 < 8; ++kb2) {
        const bf16x8 af  = *reinterpret_cast<const bf16x8*>(&aLb[kb2][l][0]);
        const bf16x8 bff = *reinterpret_cast<const bf16x8*>(&VF[((kb2*4 + wid)*64 + l)*8]);
        pacc = __builtin_amdgcn_mfma_f32_16x16x32_bf16(af, bff, pacc, 0, 0, 0);
      }
      const int b_ = bh >> 3, hh = bh & 7;
      const int colv = hh*DHEAD + wid*16 + (l & 15);
#pragma unroll
      for (int r = 0; r < 4; ++r) {
        const int row = (l >> 4)*4 + r;            // q index 0..15
        const float stot = reds[row>>2][0][row&3] + reds[row>>2][1][row&3]
                         + reds[row>>2][2][row&3] + reds[row>>2][3][row&3];
        Xb[(b_*NL + qt*16 + row)*HIDN + colv] = f2bf(pacc[r] * __builtin_amdgcn_rcpf(stot));
      }
    }
  }
}

extern "C" void kernel_launch(void* const* d_in, const int* in_sizes, int n_in,
                              void* d_out, int out_size, void* d_ws, size_t ws_size,
                              hipStream_t stream) {
  const float* query = (const float*)d_in[0];
  const float* key   = (const float*)d_in[1];
  const float* value = (const float*)d_in[2];
  const float* Wq = (const float*)d_in[3];
  const float* bq = (const float*)d_in[4];
  const float* Wk = (const float*)d_in[5];
  const float* bk = (const float*)d_in[6];
  const float* Wv = (const float*)d_in[7];
  const float* bv = (const float*)d_in[8];
  const float* W1 = (const float*)d_in[9];
  const float* b1 = (const float*)d_in[10];
  const float* W2 = (const float*)d_in[11];
  const float* b2 = (const float*)d_in[12];
  const float* va_w = (const float*)d_in[13];
  const float* Wo = (const float*)d_in[15];
  const float* bo = (const float*)d_in[16];

  float* out = (float*)d_out;
  float* ws  = (float*)d_ws;
  float* attn = out + NROW*HIDN;   // output 1: attention [B,H,Lq,Lk]

  prep<<<dim3(256, 1, 7), 256, 0, stream>>>(Wq, bq, Wk, bk, W1, b1, W2, b2,
                                            query, key, value, Wv, Wo, ws);
  mfma_proj<<<dim3(8, 16, 3), 256, 0, stream>>>(ws, bv);
  attn_kernel<<<dim3(16, 32), 1024, 0, stream>>>(ws, va_w, attn);
  mfma_out<<<dim3(8, 16), 256, 0, stream>>>(ws, bo, out);
}

// Round 7
// 66.014 us; speedup vs baseline: 5.9429x; 1.1276x over previous
//
#include <hip/hip_runtime.h>

#define HIDN 512
#define NHEAD 8
#define DHEAD 64
#define NB 4
#define NL 256
#define NROW 1024   // NB*NL

// 2*log2(e): exp(2y) = exp2(y * SCALE2)
#define SCALE2 2.8853900817779268f
#define LOG2E  1.4426950408889634f

// workspace layout (float offsets)
#define WS_WQB 0                       // fused Wq'' bf16 [512][512]   (131072 floats)
#define WS_WKB (WS_WQB + 131072)       // fused Wk'' bf16
#define WS_BQF (WS_WKB + 131072)       // fused bq'' f32 [512]
#define WS_BKF (WS_BQF + 512)          // fused bk'' f32 [512]
#define WS_QBF (WS_BKF + 512)          // query bf16 [1024][512]; reused as X bf16 after proj
#define WS_KBF (WS_QBF + 262144)       // key bf16
#define WS_VBF (WS_KBF + 262144)       // value bf16
#define WS_WVB (WS_VBF + 262144)       // Wv bf16 [512][512]
#define WS_WOB (WS_WVB + 131072)       // Wo bf16 [512][512]
#define WS_EQ  (WS_WOB + 131072)       // EQ = exp2(Qt') f32 head-major [32bh][256][64]
#define WS_EK  (WS_EQ + 524288)        // EK = exp2(Kt') f32 head-major
#define WS_VF  (WS_EK + 524288)        // V bf16 MFMA B-fragments [32bh][32tile][64lane][8j]

typedef __attribute__((ext_vector_type(4))) float f32x4;
typedef __attribute__((ext_vector_type(8))) short bf16x8;

__device__ __forceinline__ short f2bf(float x) {
  unsigned u = __float_as_uint(x);
  u += 0x7fffu + ((u >> 16) & 1u);   // RNE
  return (short)(u >> 16);
}

// ---------------- prep: z=0/1 fold W1/W2 (+SCALE2) into Wq/Wk -> bf16; z=2..6 f32->bf16 copies
__global__ __launch_bounds__(256) void prep(
    const float* __restrict__ Wq, const float* __restrict__ bq,
    const float* __restrict__ Wk, const float* __restrict__ bk,
    const float* __restrict__ W1, const float* __restrict__ b1,
    const float* __restrict__ W2, const float* __restrict__ b2,
    const float* __restrict__ q, const float* __restrict__ k, const float* __restrict__ v,
    const float* __restrict__ Wv, const float* __restrict__ Wo,
    float* __restrict__ ws)
{
  const int z = blockIdx.z;
  if (z >= 2) {
    const int zz = z - 2;
    const float* src; short* dst; int n;
    if (zz == 0)      { src = q;  dst = (short*)(ws + WS_QBF); n = 524288; }
    else if (zz == 1) { src = k;  dst = (short*)(ws + WS_KBF); n = 524288; }
    else if (zz == 2) { src = v;  dst = (short*)(ws + WS_VBF); n = 524288; }
    else if (zz == 3) { src = Wv; dst = (short*)(ws + WS_WVB); n = 262144; }
    else              { src = Wo; dst = (short*)(ws + WS_WOB); n = 262144; }
    const int i = (blockIdx.x * 256 + threadIdx.x) * 8;
    if (i >= n) return;
    const float4 a = *reinterpret_cast<const float4*>(src + i);
    const float4 b = *reinterpret_cast<const float4*>(src + i + 4);
    bf16x8 o;
    o[0] = f2bf(a.x); o[1] = f2bf(a.y); o[2] = f2bf(a.z); o[3] = f2bf(a.w);
    o[4] = f2bf(b.x); o[5] = f2bf(b.y); o[6] = f2bf(b.z); o[7] = f2bf(b.w);
    *reinterpret_cast<bf16x8*>(dst + i) = o;
    return;
  }

  if (blockIdx.x >= 128) return;
  const int c0 = (blockIdx.x & 3) * 128;
  const int y  = blockIdx.x >> 2;
  const int h  = y >> 2;
  const int ig = y & 3;                // 16-row group within head
  const int which = z;
  const float* Wsrc = which ? Wk : Wq;
  const float* bsrc = which ? bk : bq;
  const float* Wt   = which ? W2 : W1;
  const float* bt   = which ? b2 : b1;
  short* Wout = reinterpret_cast<short*>(ws + (which ? WS_WKB : WS_WQB));
  float* bout = ws + (which ? WS_BKF : WS_BQF);

  __shared__ float Wtl[16][68];
  for (int t = threadIdx.x; t < 16*64; t += 256)
    Wtl[t >> 6][t & 63] = Wt[(ig*16 + (t >> 6))*64 + (t & 63)];
  __syncthreads();

  const int c  = c0 + (threadIdx.x & 127);
  const int i0 = (threadIdx.x >> 7) * 8;   // local row base (0 or 8)
  float acc[8];
#pragma unroll
  for (int ii = 0; ii < 8; ++ii) acc[ii] = 0.f;

  for (int j0 = 0; j0 < 64; j0 += 4) {
    const float s0 = Wsrc[(h*64 + j0 + 0)*HIDN + c];
    const float s1 = Wsrc[(h*64 + j0 + 1)*HIDN + c];
    const float s2 = Wsrc[(h*64 + j0 + 2)*HIDN + c];
    const float s3 = Wsrc[(h*64 + j0 + 3)*HIDN + c];
#pragma unroll
    for (int ii = 0; ii < 8; ++ii) {
      const float4 wv4 = *reinterpret_cast<const float4*>(&Wtl[i0+ii][j0]);
      float a = acc[ii];
      a = fmaf(wv4.x, s0, a);
      a = fmaf(wv4.y, s1, a);
      a = fmaf(wv4.z, s2, a);
      a = fmaf(wv4.w, s3, a);
      acc[ii] = a;
    }
  }
#pragma unroll
  for (int ii = 0; ii < 8; ++ii)
    Wout[(h*64 + ig*16 + i0 + ii)*HIDN + c] = f2bf(acc[ii] * SCALE2);

  if (blockIdx.x == 0 && threadIdx.x < 16) {
    const int il = threadIdx.x;
    float a = bt[ig*16 + il];
    for (int j = 0; j < 64; ++j)
      a = fmaf(Wtl[il][j], bsrc[h*64 + j], a);
    bout[h*64 + ig*16 + il] = a * SCALE2;
  }
}

// ---------------- mfma_proj: C = A(bf16) @ W(bf16)^T + bias ----------------
// LDS-free: fragments loaded directly from row-major global (L2-resident).
// z=0 -> EQ = exp2(Qt'+b) f32; z=1 -> EK = exp2(Kt'+b) f32; z=2 -> VF bf16 fragments.
__global__ __launch_bounds__(256) void mfma_proj(float* __restrict__ ws, const float* __restrict__ bv)
{
  const int z = blockIdx.z;
  const short* A; const short* W; const float* bias;
  if (z == 0)      { A = (const short*)(ws + WS_QBF); W = (const short*)(ws + WS_WQB); bias = ws + WS_BQF; }
  else if (z == 1) { A = (const short*)(ws + WS_KBF); W = (const short*)(ws + WS_WKB); bias = ws + WS_BKF; }
  else             { A = (const short*)(ws + WS_VBF); W = (const short*)(ws + WS_WVB); bias = bv; }

  const int wid  = threadIdx.x >> 6;
  const int lane = threadIdx.x & 63;
  const int mt = blockIdx.y * 4 + wid;     // m-tile 0..63
  const int nb = blockIdx.x * 64;          // n base
  const short* aptr = A + (mt*16 + (lane & 15))*HIDN + (lane >> 4)*8;
  const short* wptr = W + (nb + (lane & 15))*HIDN + (lane >> 4)*8;

  f32x4 acc[4] = {{0,0,0,0},{0,0,0,0},{0,0,0,0},{0,0,0,0}};
#pragma unroll 4
  for (int k0 = 0; k0 < HIDN; k0 += 32) {
    const bf16x8 af = *reinterpret_cast<const bf16x8*>(aptr + k0);
    const short* wp = wptr + k0;
#pragma unroll
    for (int t = 0; t < 4; ++t)
      acc[t] = __builtin_amdgcn_mfma_f32_16x16x32_bf16(
          af, *reinterpret_cast<const bf16x8*>(wp + t*16*HIDN), acc[t], 0, 0, 0);
  }

  const int rbase = mt*16 + (lane >> 4)*4;
  if (z < 2) {
    // store EQ/EK = exp2(proj + bias); weights carry the 2*log2(e) prescale
    float* dst = ws + (z == 0 ? WS_EQ : WS_EK);
#pragma unroll
    for (int t = 0; t < 4; ++t) {
      const int c = nb + t*16 + (lane & 15);
      const float bc = bias[c];
      const int hh = c >> 6, d = c & 63;
#pragma unroll
      for (int r = 0; r < 4; ++r) {
        const int R = rbase + r;
        dst[(((R >> 8)*NHEAD + hh)*NL + (R & 255))*DHEAD + d] =
            __builtin_amdgcn_exp2f(acc[t][r] + bc);
      }
    }
  } else {
    short* vf = reinterpret_cast<short*>(ws + WS_VF);
#pragma unroll
    for (int t = 0; t < 4; ++t) {
      const int c = nb + t*16 + (lane & 15);
      const float bc = bias[c];
      const int hh = c >> 6, d = c & 63;
#pragma unroll
      for (int r = 0; r < 4; ++r) {
        const int R = rbase + r;
        const int l = R & 255;
        const int bh = (R >> 8)*NHEAD + hh;
        const int tile = ((l >> 5) << 2) + (d >> 4);
        const int lanep = (((l >> 3) & 3) << 4) + (d & 15);
        vf[((bh*32 + tile)*64 + lanep)*8 + (l & 7)] = f2bf(acc[t][r] + bc);
      }
    }
  }
}

// ---------------- mfma_out: out = X(bf16) @ Wo(bf16)^T + bo, f32 row-major ----------------
__global__ __launch_bounds__(256) void mfma_out(
    float* __restrict__ ws, const float* __restrict__ bo, float* __restrict__ out)
{
  const short* A = (const short*)(ws + WS_QBF);   // X bf16 (reused region)
  const short* W = (const short*)(ws + WS_WOB);
  const int wid  = threadIdx.x >> 6;
  const int lane = threadIdx.x & 63;
  const int mt = blockIdx.y * 4 + wid;
  const int nb = blockIdx.x * 64;
  const short* aptr = A + (mt*16 + (lane & 15))*HIDN + (lane >> 4)*8;
  const short* wptr = W + (nb + (lane & 15))*HIDN + (lane >> 4)*8;

  f32x4 acc[4] = {{0,0,0,0},{0,0,0,0},{0,0,0,0},{0,0,0,0}};
#pragma unroll 4
  for (int k0 = 0; k0 < HIDN; k0 += 32) {
    const bf16x8 af = *reinterpret_cast<const bf16x8*>(aptr + k0);
    const short* wp = wptr + k0;
#pragma unroll
    for (int t = 0; t < 4; ++t)
      acc[t] = __builtin_amdgcn_mfma_f32_16x16x32_bf16(
          af, *reinterpret_cast<const bf16x8*>(wp + t*16*HIDN), acc[t], 0, 0, 0);
  }

  const int rbase = mt*16 + (lane >> 4)*4;
#pragma unroll
  for (int t = 0; t < 4; ++t) {
    const int c = nb + t*16 + (lane & 15);
    const float bc = bo[c];
#pragma unroll
    for (int r = 0; r < 4; ++r)
      out[(rbase + r)*HIDN + c] = acc[t][r] + bc;
  }
}

// ---------------- attn: energy (factorized exp) + (no-max) softmax + MFMA PV ----------------
// grid (16 qtiles, 32 bh), 1024 threads. Group g=tid>>8 owns q-rows g*4..g*4+3;
// thread lk=tid&255 owns key lk. sigma = 1/(1 + EQ*EK): one trans op per eval.
__global__ __launch_bounds__(1024, 8) void attn_kernel(
    float* __restrict__ ws, const float* __restrict__ va_w,
    float* __restrict__ attn_out)
{
  const int qt = blockIdx.x;
  const int bh = blockIdx.y;
  const int tid = threadIdx.x;

  __shared__ __align__(16) short aLb[8][64][8];      // 8 KB  P as bf16 A-fragments
  __shared__ __align__(16) float Eql[16][64];        // 4 KB  EQ rows for this qtile
  __shared__ __align__(16) float vaS[64];
  __shared__ __align__(16) float reds[4][4][4];      // [qgroup][wave][qi]

  const float* EQ  = ws + WS_EQ + (bh*NL + qt*16)*DHEAD;
  const float* EKB = ws + WS_EK + bh*NL*DHEAD;
  const short* VF  = reinterpret_cast<const short*>(ws + WS_VF) + bh*32*64*8;
  short* Xb = reinterpret_cast<short*>(ws + WS_QBF);

  if (tid < 256)
    reinterpret_cast<float4*>(Eql)[tid] = reinterpret_cast<const float4*>(EQ)[tid];
  if (tid >= 1024-64) vaS[tid & 63] = -2.0f * va_w[tid & 63];

  const int g  = tid >> 8;        // q-group: rows g*4 .. g*4+3
  const int lk = tid & 255;
  const int wv = lk >> 6;
  const int l  = lk & 63;
  const float* EkRow = EKB + lk*DHEAD;
  __syncthreads();

  float acc[4];
#pragma unroll
  for (int qi = 0; qi < 4; ++qi) acc[qi] = 0.f;

#pragma unroll 1
  for (int d0 = 0; d0 < 64; d0 += 8) {
    const f32x4 ea = *reinterpret_cast<const f32x4*>(EkRow + d0);
    const f32x4 eb = *reinterpret_cast<const f32x4*>(EkRow + d0 + 4);
    const f32x4 vaA = *reinterpret_cast<const f32x4*>(&vaS[d0]);
    const f32x4 vaB = *reinterpret_cast<const f32x4*>(&vaS[d0 + 4]);
#pragma unroll
    for (int qi = 0; qi < 4; ++qi) {
      const f32x4 qa = *reinterpret_cast<const f32x4*>(&Eql[g*4+qi][d0]);
      const f32x4 qb = *reinterpret_cast<const f32x4*>(&Eql[g*4+qi][d0 + 4]);
      float a = acc[qi];
      a = fmaf(vaA.x, __builtin_amdgcn_rcpf(fmaf(qa.x, ea.x, 1.0f)), a);
      a = fmaf(vaA.y, __builtin_amdgcn_rcpf(fmaf(qa.y, ea.y, 1.0f)), a);
      a = fmaf(vaA.z, __builtin_amdgcn_rcpf(fmaf(qa.z, ea.z, 1.0f)), a);
      a = fmaf(vaA.w, __builtin_amdgcn_rcpf(fmaf(qa.w, ea.w, 1.0f)), a);
      a = fmaf(vaB.x, __builtin_amdgcn_rcpf(fmaf(qb.x, eb.x, 1.0f)), a);
      a = fmaf(vaB.y, __builtin_amdgcn_rcpf(fmaf(qb.y, eb.y, 1.0f)), a);
      a = fmaf(vaB.z, __builtin_amdgcn_rcpf(fmaf(qb.z, eb.z, 1.0f)), a);
      a = fmaf(vaB.w, __builtin_amdgcn_rcpf(fmaf(qb.w, eb.w, 1.0f)), a);
      acc[qi] = a;
    }
  }

  // p = exp(e)  (|e| <= ~2*sum|va| ~ 8 -> no max shift needed)
  float p[4];
#pragma unroll
  for (int qi = 0; qi < 4; ++qi)
    p[qi] = __builtin_amdgcn_exp2f(acc[qi] * LOG2E);

#pragma unroll
  for (int qi = 0; qi < 4; ++qi) {
    float s = p[qi];
#pragma unroll
    for (int off = 1; off < 64; off <<= 1)
      s += __shfl_xor(s, off);
    if (l == 0) reds[g][wv][qi] = s;
  }
  // publish P as bf16 A-fragments
  {
    const int kb2 = lk >> 5;
    const int lbase = ((lk >> 3) & 3) * 16;
    const int jb = lk & 7;
#pragma unroll
    for (int qi = 0; qi < 4; ++qi)
      aLb[kb2][lbase + g*4 + qi][jb] = f2bf(p[qi]);
  }
  __syncthreads();

  // totals + attention output
  {
    f32x4 s4 = {0.f,0.f,0.f,0.f};
#pragma unroll
    for (int w2 = 0; w2 < 4; ++w2)
      s4 += *reinterpret_cast<const f32x4*>(&reds[g][w2][0]);
    float inv[4];
    inv[0] = __builtin_amdgcn_rcpf(s4.x); inv[1] = __builtin_amdgcn_rcpf(s4.y);
    inv[2] = __builtin_amdgcn_rcpf(s4.z); inv[3] = __builtin_amdgcn_rcpf(s4.w);
#pragma unroll
    for (int qi = 0; qi < 4; ++qi)
      attn_out[(bh*NL + qt*16 + g*4 + qi)*NL + lk] = p[qi] * inv[qi];

    // PV via MFMA: waves 0..3 (wid = d-block), V B-fragments from global (L2-hot)
    const int wid = tid >> 6;
    if (wid < 4) {
      f32x4 pacc = {0.f,0.f,0.f,0.f};
#pragma unroll
      for (int kb2 = 0; kb2 < 8; ++kb2) {
        const bf16x8 af  = *reinterpret_cast<const bf16x8*>(&aLb[kb2][l][0]);
        const bf16x8 bff = *reinterpret_cast<const bf16x8*>(&VF[((kb2*4 + wid)*64 + l)*8]);
        pacc = __builtin_amdgcn_mfma_f32_16x16x32_bf16(af, bff, pacc, 0, 0, 0);
      }
      const int b_ = bh >> 3, hh = bh & 7;
      const int colv = hh*DHEAD + wid*16 + (l & 15);
#pragma unroll
      for (int r = 0; r < 4; ++r) {
        const int row = (l >> 4)*4 + r;            // q index 0..15
        const float stot = reds[row>>2][0][row&3] + reds[row>>2][1][row&3]
                         + reds[row>>2][2][row&3] + reds[row>>2][3][row&3];
        Xb[(b_*NL + qt*16 + row)*HIDN + colv] = f2bf(pacc[r] * __builtin_amdgcn_rcpf(stot));
      }
    }
  }
}

extern "C" void kernel_launch(void* const* d_in, const int* in_sizes, int n_in,
                              void* d_out, int out_size, void* d_ws, size_t ws_size,
                              hipStream_t stream) {
  const float* query = (const float*)d_in[0];
  const float* key   = (const float*)d_in[1];
  const float* value = (const float*)d_in[2];
  const float* Wq = (const float*)d_in[3];
  const float* bq = (const float*)d_in[4];
  const float* Wk = (const float*)d_in[5];
  const float* bk = (const float*)d_in[6];
  const float* Wv = (const float*)d_in[7];
  const float* bv = (const float*)d_in[8];
  const float* W1 = (const float*)d_in[9];
  const float* b1 = (const float*)d_in[10];
  const float* W2 = (const float*)d_in[11];
  const float* b2 = (const float*)d_in[12];
  const float* va_w = (const float*)d_in[13];
  const float* Wo = (const float*)d_in[15];
  const float* bo = (const float*)d_in[16];

  float* out = (float*)d_out;
  float* ws  = (float*)d_ws;
  float* attn = out + NROW*HIDN;   // output 1: attention [B,H,Lq,Lk]

  prep<<<dim3(256, 1, 7), 256, 0, stream>>>(Wq, bq, Wk, bk, W1, b1, W2, b2,
                                            query, key, value, Wv, Wo, ws);
  mfma_proj<<<dim3(8, 16, 3), 256, 0, stream>>>(ws, bv);
  attn_kernel<<<dim3(16, 32), 1024, 0, stream>>>(ws, va_w, attn);
  mfma_out<<<dim3(8, 16), 256, 0, stream>>>(ws, bo, out);
}

// Round 8
// 64.267 us; speedup vs baseline: 6.1044x; 1.0272x over previous
//
#include <hip/hip_runtime.h>

#define HIDN 512
#define NHEAD 8
#define DHEAD 64
#define NB 4
#define NL 256
#define NROW 1024   // NB*NL

// 2*log2(e): exp(2y) = exp2(y * SCALE2)
#define SCALE2 2.8853900817779268f
#define LOG2E  1.4426950408889634f

// workspace layout (float offsets)
#define WS_WQB 0                       // fused Wq'' bf16 [512][512]   (131072 floats)
#define WS_WKB (WS_WQB + 131072)       // fused Wk'' bf16
#define WS_BQF (WS_WKB + 131072)       // fused bq'' f32 [512]
#define WS_BKF (WS_BQF + 512)          // fused bk'' f32 [512]
#define WS_QBF (WS_BKF + 512)          // query bf16 [1024][512]; reused as X bf16 after proj
#define WS_KBF (WS_QBF + 262144)       // key bf16
#define WS_VBF (WS_KBF + 262144)       // value bf16
#define WS_WVB (WS_VBF + 262144)       // Wv bf16 [512][512]
#define WS_WOB (WS_WVB + 131072)       // Wo bf16 [512][512]
#define WS_EQ  (WS_WOB + 131072)       // EQ = exp2(Qt') f32 head-major [32bh][256][64]
#define WS_EK  (WS_EQ + 524288)        // EK = exp2(Kt') f32 head-major
#define WS_VF  (WS_EK + 524288)        // V bf16 MFMA B-fragments [32bh][32tile][64lane][8j]

typedef __attribute__((ext_vector_type(4))) float f32x4;
typedef __attribute__((ext_vector_type(8))) short bf16x8;

__device__ __forceinline__ short f2bf(float x) {
  unsigned u = __float_as_uint(x);
  u += 0x7fffu + ((u >> 16) & 1u);   // RNE
  return (short)(u >> 16);
}

// ---------------- prep: z=0/1 fold W1/W2 (+SCALE2) into Wq/Wk -> bf16; z=2..6 f32->bf16 copies
__global__ __launch_bounds__(256) void prep(
    const float* __restrict__ Wq, const float* __restrict__ bq,
    const float* __restrict__ Wk, const float* __restrict__ bk,
    const float* __restrict__ W1, const float* __restrict__ b1,
    const float* __restrict__ W2, const float* __restrict__ b2,
    const float* __restrict__ q, const float* __restrict__ k, const float* __restrict__ v,
    const float* __restrict__ Wv, const float* __restrict__ Wo,
    float* __restrict__ ws)
{
  const int z = blockIdx.z;
  if (z >= 2) {
    const int zz = z - 2;
    const float* src; short* dst; int n;
    if (zz == 0)      { src = q;  dst = (short*)(ws + WS_QBF); n = 524288; }
    else if (zz == 1) { src = k;  dst = (short*)(ws + WS_KBF); n = 524288; }
    else if (zz == 2) { src = v;  dst = (short*)(ws + WS_VBF); n = 524288; }
    else if (zz == 3) { src = Wv; dst = (short*)(ws + WS_WVB); n = 262144; }
    else              { src = Wo; dst = (short*)(ws + WS_WOB); n = 262144; }
    const int i = (blockIdx.x * 256 + threadIdx.x) * 8;
    if (i >= n) return;
    const float4 a = *reinterpret_cast<const float4*>(src + i);
    const float4 b = *reinterpret_cast<const float4*>(src + i + 4);
    bf16x8 o;
    o[0] = f2bf(a.x); o[1] = f2bf(a.y); o[2] = f2bf(a.z); o[3] = f2bf(a.w);
    o[4] = f2bf(b.x); o[5] = f2bf(b.y); o[6] = f2bf(b.z); o[7] = f2bf(b.w);
    *reinterpret_cast<bf16x8*>(dst + i) = o;
    return;
  }

  if (blockIdx.x >= 128) return;
  const int c0 = (blockIdx.x & 3) * 128;
  const int y  = blockIdx.x >> 2;
  const int h  = y >> 2;
  const int ig = y & 3;                // 16-row group within head
  const int which = z;
  const float* Wsrc = which ? Wk : Wq;
  const float* bsrc = which ? bk : bq;
  const float* Wt   = which ? W2 : W1;
  const float* bt   = which ? b2 : b1;
  short* Wout = reinterpret_cast<short*>(ws + (which ? WS_WKB : WS_WQB));
  float* bout = ws + (which ? WS_BKF : WS_BQF);

  __shared__ float Wtl[16][68];
  for (int t = threadIdx.x; t < 16*64; t += 256)
    Wtl[t >> 6][t & 63] = Wt[(ig*16 + (t >> 6))*64 + (t & 63)];
  __syncthreads();

  const int c  = c0 + (threadIdx.x & 127);
  const int i0 = (threadIdx.x >> 7) * 8;   // local row base (0 or 8)
  float acc[8];
#pragma unroll
  for (int ii = 0; ii < 8; ++ii) acc[ii] = 0.f;

  for (int j0 = 0; j0 < 64; j0 += 4) {
    const float s0 = Wsrc[(h*64 + j0 + 0)*HIDN + c];
    const float s1 = Wsrc[(h*64 + j0 + 1)*HIDN + c];
    const float s2 = Wsrc[(h*64 + j0 + 2)*HIDN + c];
    const float s3 = Wsrc[(h*64 + j0 + 3)*HIDN + c];
#pragma unroll
    for (int ii = 0; ii < 8; ++ii) {
      const float4 wv4 = *reinterpret_cast<const float4*>(&Wtl[i0+ii][j0]);
      float a = acc[ii];
      a = fmaf(wv4.x, s0, a);
      a = fmaf(wv4.y, s1, a);
      a = fmaf(wv4.z, s2, a);
      a = fmaf(wv4.w, s3, a);
      acc[ii] = a;
    }
  }
#pragma unroll
  for (int ii = 0; ii < 8; ++ii)
    Wout[(h*64 + ig*16 + i0 + ii)*HIDN + c] = f2bf(acc[ii] * SCALE2);

  if (blockIdx.x == 0 && threadIdx.x < 16) {
    const int il = threadIdx.x;
    float a = bt[ig*16 + il];
    for (int j = 0; j < 64; ++j)
      a = fmaf(Wtl[il][j], bsrc[h*64 + j], a);
    bout[h*64 + ig*16 + il] = a * SCALE2;
  }
}

// ---------------- mfma_proj: C = A(bf16) @ W(bf16)^T + bias ----------------
// LDS-free: fragments loaded directly from row-major global (L2-resident).
// z=0 -> EQ = exp2(Qt'+b) f32; z=1 -> EK = exp2(Kt'+b) f32; z=2 -> VF bf16 fragments.
__global__ __launch_bounds__(256) void mfma_proj(float* __restrict__ ws, const float* __restrict__ bv)
{
  const int z = blockIdx.z;
  const short* A; const short* W; const float* bias;
  if (z == 0)      { A = (const short*)(ws + WS_QBF); W = (const short*)(ws + WS_WQB); bias = ws + WS_BQF; }
  else if (z == 1) { A = (const short*)(ws + WS_KBF); W = (const short*)(ws + WS_WKB); bias = ws + WS_BKF; }
  else             { A = (const short*)(ws + WS_VBF); W = (const short*)(ws + WS_WVB); bias = bv; }

  const int wid  = threadIdx.x >> 6;
  const int lane = threadIdx.x & 63;
  const int mt = blockIdx.y * 4 + wid;     // m-tile 0..63
  const int nb = blockIdx.x * 64;          // n base
  const short* aptr = A + (mt*16 + (lane & 15))*HIDN + (lane >> 4)*8;
  const short* wptr = W + (nb + (lane & 15))*HIDN + (lane >> 4)*8;

  f32x4 acc[4] = {{0,0,0,0},{0,0,0,0},{0,0,0,0},{0,0,0,0}};
#pragma unroll 4
  for (int k0 = 0; k0 < HIDN; k0 += 32) {
    const bf16x8 af = *reinterpret_cast<const bf16x8*>(aptr + k0);
    const short* wp = wptr + k0;
#pragma unroll
    for (int t = 0; t < 4; ++t)
      acc[t] = __builtin_amdgcn_mfma_f32_16x16x32_bf16(
          af, *reinterpret_cast<const bf16x8*>(wp + t*16*HIDN), acc[t], 0, 0, 0);
  }

  const int rbase = mt*16 + (lane >> 4)*4;
  if (z < 2) {
    // store EQ/EK = exp2(proj + bias); weights carry the 2*log2(e) prescale
    float* dst = ws + (z == 0 ? WS_EQ : WS_EK);
#pragma unroll
    for (int t = 0; t < 4; ++t) {
      const int c = nb + t*16 + (lane & 15);
      const float bc = bias[c];
      const int hh = c >> 6, d = c & 63;
#pragma unroll
      for (int r = 0; r < 4; ++r) {
        const int R = rbase + r;
        dst[(((R >> 8)*NHEAD + hh)*NL + (R & 255))*DHEAD + d] =
            __builtin_amdgcn_exp2f(acc[t][r] + bc);
      }
    }
  } else {
    short* vf = reinterpret_cast<short*>(ws + WS_VF);
#pragma unroll
    for (int t = 0; t < 4; ++t) {
      const int c = nb + t*16 + (lane & 15);
      const float bc = bias[c];
      const int hh = c >> 6, d = c & 63;
#pragma unroll
      for (int r = 0; r < 4; ++r) {
        const int R = rbase + r;
        const int l = R & 255;
        const int bh = (R >> 8)*NHEAD + hh;
        const int tile = ((l >> 5) << 2) + (d >> 4);
        const int lanep = (((l >> 3) & 3) << 4) + (d & 15);
        vf[((bh*32 + tile)*64 + lanep)*8 + (l & 7)] = f2bf(acc[t][r] + bc);
      }
    }
  }
}

// ---------------- mfma_out: out = X(bf16) @ Wo(bf16)^T + bo, f32 row-major ----------------
// 32-wide n-split: grid (16,16), 1024 waves (2x the old 512) for latency hiding.
__global__ __launch_bounds__(256) void mfma_out(
    float* __restrict__ ws, const float* __restrict__ bo, float* __restrict__ out)
{
  const short* A = (const short*)(ws + WS_QBF);   // X bf16 (reused region)
  const short* W = (const short*)(ws + WS_WOB);
  const int wid  = threadIdx.x >> 6;
  const int lane = threadIdx.x & 63;
  const int mt = blockIdx.y * 4 + wid;     // 0..63
  const int nb = blockIdx.x * 32;          // 0..480
  const short* aptr = A + (mt*16 + (lane & 15))*HIDN + (lane >> 4)*8;
  const short* wptr = W + (nb + (lane & 15))*HIDN + (lane >> 4)*8;

  f32x4 acc[2] = {{0,0,0,0},{0,0,0,0}};
#pragma unroll 4
  for (int k0 = 0; k0 < HIDN; k0 += 32) {
    const bf16x8 af = *reinterpret_cast<const bf16x8*>(aptr + k0);
    const short* wp = wptr + k0;
#pragma unroll
    for (int t = 0; t < 2; ++t)
      acc[t] = __builtin_amdgcn_mfma_f32_16x16x32_bf16(
          af, *reinterpret_cast<const bf16x8*>(wp + t*16*HIDN), acc[t], 0, 0, 0);
  }

  const int rbase = mt*16 + (lane >> 4)*4;
#pragma unroll
  for (int t = 0; t < 2; ++t) {
    const int c = nb + t*16 + (lane & 15);
    const float bc = bo[c];
#pragma unroll
    for (int r = 0; r < 4; ++r)
      out[(rbase + r)*HIDN + c] = acc[t][r] + bc;
  }
}

// ---------------- attn: paired-rcp energy + (no-max) softmax + MFMA PV ----------------
// grid (16 qtiles, 32 bh), 1024 threads. Group g=tid>>8 owns q-rows g*4..g*4+3;
// thread lk=tid&255 owns key lk. Two sigma terms share one rcp:
//   va0/t0 + va1/t1 = (va0*t1 + va1*t0) * rcp(t0*t1),  t = 1 + EQ*EK  (t in [1,2^34])
__global__ __launch_bounds__(1024, 4) void attn_kernel(
    float* __restrict__ ws, const float* __restrict__ va_w,
    float* __restrict__ attn_out)
{
  const int qt = blockIdx.x;
  const int bh = blockIdx.y;
  const int tid = threadIdx.x;

  __shared__ __align__(16) short aLb[8][64][8];      // 8 KB  P as bf16 A-fragments
  __shared__ __align__(16) float Eql[16][64];        // 4 KB  EQ rows for this qtile
  __shared__ __align__(16) float vaS[64];
  __shared__ __align__(16) float reds[4][4][4];      // [qgroup][wave][qi]

  const float* EQ  = ws + WS_EQ + (bh*NL + qt*16)*DHEAD;
  const float* EKB = ws + WS_EK + bh*NL*DHEAD;
  const short* VF  = reinterpret_cast<const short*>(ws + WS_VF) + bh*32*64*8;
  short* Xb = reinterpret_cast<short*>(ws + WS_QBF);

  if (tid < 256)
    reinterpret_cast<float4*>(Eql)[tid] = reinterpret_cast<const float4*>(EQ)[tid];
  if (tid >= 1024-64) vaS[tid & 63] = -2.0f * va_w[tid & 63];

  const int g  = tid >> 8;        // q-group: rows g*4 .. g*4+3
  const int lk = tid & 255;
  const int wv = lk >> 6;
  const int l  = lk & 63;
  const float* EkRow = EKB + lk*DHEAD;
  __syncthreads();

  float acc[4];
#pragma unroll
  for (int qi = 0; qi < 4; ++qi) acc[qi] = 0.f;

#pragma unroll 1
  for (int d0 = 0; d0 < 64; d0 += 8) {
    const f32x4 ea = *reinterpret_cast<const f32x4*>(EkRow + d0);
    const f32x4 eb = *reinterpret_cast<const f32x4*>(EkRow + d0 + 4);
    const f32x4 vaA = *reinterpret_cast<const f32x4*>(&vaS[d0]);
    const f32x4 vaB = *reinterpret_cast<const f32x4*>(&vaS[d0 + 4]);
#pragma unroll
    for (int qi = 0; qi < 4; ++qi) {
      const f32x4 qa = *reinterpret_cast<const f32x4*>(&Eql[g*4+qi][d0]);
      const f32x4 qb = *reinterpret_cast<const f32x4*>(&Eql[g*4+qi][d0 + 4]);
      const float t0 = fmaf(qa.x, ea.x, 1.0f);
      const float t1 = fmaf(qa.y, ea.y, 1.0f);
      const float t2 = fmaf(qa.z, ea.z, 1.0f);
      const float t3 = fmaf(qa.w, ea.w, 1.0f);
      const float t4 = fmaf(qb.x, eb.x, 1.0f);
      const float t5 = fmaf(qb.y, eb.y, 1.0f);
      const float t6 = fmaf(qb.z, eb.z, 1.0f);
      const float t7 = fmaf(qb.w, eb.w, 1.0f);
      float a = acc[qi];
      a = fmaf(fmaf(vaA.x, t1, vaA.y * t0), __builtin_amdgcn_rcpf(t0 * t1), a);
      a = fmaf(fmaf(vaA.z, t3, vaA.w * t2), __builtin_amdgcn_rcpf(t2 * t3), a);
      a = fmaf(fmaf(vaB.x, t5, vaB.y * t4), __builtin_amdgcn_rcpf(t4 * t5), a);
      a = fmaf(fmaf(vaB.z, t7, vaB.w * t6), __builtin_amdgcn_rcpf(t6 * t7), a);
      acc[qi] = a;
    }
  }

  // p = exp(e)  (|e| <= ~2*sum|va| ~ 8 -> no max shift needed)
  float p[4];
#pragma unroll
  for (int qi = 0; qi < 4; ++qi)
    p[qi] = __builtin_amdgcn_exp2f(acc[qi] * LOG2E);

#pragma unroll
  for (int qi = 0; qi < 4; ++qi) {
    float s = p[qi];
#pragma unroll
    for (int off = 1; off < 64; off <<= 1)
      s += __shfl_xor(s, off);
    if (l == 0) reds[g][wv][qi] = s;
  }
  // publish P as bf16 A-fragments
  {
    const int kb2 = lk >> 5;
    const int lbase = ((lk >> 3) & 3) * 16;
    const int jb = lk & 7;
#pragma unroll
    for (int qi = 0; qi < 4; ++qi)
      aLb[kb2][lbase + g*4 + qi][jb] = f2bf(p[qi]);
  }
  __syncthreads();

  // totals + attention output
  {
    f32x4 s4 = {0.f,0.f,0.f,0.f};
#pragma unroll
    for (int w2 = 0; w2 < 4; ++w2)
      s4 += *reinterpret_cast<const f32x4*>(&reds[g][w2][0]);
    float inv[4];
    inv[0] = __builtin_amdgcn_rcpf(s4.x); inv[1] = __builtin_amdgcn_rcpf(s4.y);
    inv[2] = __builtin_amdgcn_rcpf(s4.z); inv[3] = __builtin_amdgcn_rcpf(s4.w);
#pragma unroll
    for (int qi = 0; qi < 4; ++qi)
      attn_out[(bh*NL + qt*16 + g*4 + qi)*NL + lk] = p[qi] * inv[qi];

    // PV via MFMA: waves 0..3 (wid = d-block), V B-fragments from global (L2-hot)
    const int wid = tid >> 6;
    if (wid < 4) {
      f32x4 pacc = {0.f,0.f,0.f,0.f};
#pragma unroll
      for (int kb2 = 0; kb2 < 8; ++kb2) {
        const bf16x8 af  = *reinterpret_cast<const bf16x8*>(&aLb[kb2][l][0]);
        const bf16x8 bff = *reinterpret_cast<const bf16x8*>(&VF[((kb2*4 + wid)*64 + l)*8]);
        pacc = __builtin_amdgcn_mfma_f32_16x16x32_bf16(af, bff, pacc, 0, 0, 0);
      }
      const int b_ = bh >> 3, hh = bh & 7;
      const int colv = hh*DHEAD + wid*16 + (l & 15);
#pragma unroll
      for (int r = 0; r < 4; ++r) {
        const int row = (l >> 4)*4 + r;            // q index 0..15
        const float stot = reds[row>>2][0][row&3] + reds[row>>2][1][row&3]
                         + reds[row>>2][2][row&3] + reds[row>>2][3][row&3];
        Xb[(b_*NL + qt*16 + row)*HIDN + colv] = f2bf(pacc[r] * __builtin_amdgcn_rcpf(stot));
      }
    }
  }
}

extern "C" void kernel_launch(void* const* d_in, const int* in_sizes, int n_in,
                              void* d_out, int out_size, void* d_ws, size_t ws_size,
                              hipStream_t stream) {
  const float* query = (const float*)d_in[0];
  const float* key   = (const float*)d_in[1];
  const float* value = (const float*)d_in[2];
  const float* Wq = (const float*)d_in[3];
  const float* bq = (const float*)d_in[4];
  const float* Wk = (const float*)d_in[5];
  const float* bk = (const float*)d_in[6];
  const float* Wv = (const float*)d_in[7];
  const float* bv = (const float*)d_in[8];
  const float* W1 = (const float*)d_in[9];
  const float* b1 = (const float*)d_in[10];
  const float* W2 = (const float*)d_in[11];
  const float* b2 = (const float*)d_in[12];
  const float* va_w = (const float*)d_in[13];
  const float* Wo = (const float*)d_in[15];
  const float* bo = (const float*)d_in[16];

  float* out = (float*)d_out;
  float* ws  = (float*)d_ws;
  float* attn = out + NROW*HIDN;   // output 1: attention [B,H,Lq,Lk]

  prep<<<dim3(256, 1, 7), 256, 0, stream>>>(Wq, bq, Wk, bk, W1, b1, W2, b2,
                                            query, key, value, Wv, Wo, ws);
  mfma_proj<<<dim3(8, 16, 3), 256, 0, stream>>>(ws, bv);
  attn_kernel<<<dim3(16, 32), 1024, 0, stream>>>(ws, va_w, attn);
  mfma_out<<<dim3(16, 16), 256, 0, stream>>>(ws, bo, out);
}

// Round 9
// 59.664 us; speedup vs baseline: 6.5753x; 1.0771x over previous
//
#include <hip/hip_runtime.h>

#define HIDN 512
#define NHEAD 8
#define DHEAD 64
#define NB 4
#define NL 256
#define NROW 1024   // NB*NL

// 2*log2(e): exp(2y) = exp2(y * SCALE2)
#define SCALE2 2.8853900817779268f
#define LOG2E  1.4426950408889634f
#define NEG2LOG2E -2.8853900817779268f

// workspace layout (float offsets)
#define WS_WQB 0                       // fused Wq'' bf16 [512][512]   (131072 floats)
#define WS_WKB (WS_WQB + 131072)       // fused Wk'' bf16
#define WS_BQF (WS_WKB + 131072)       // fused bq'' f32 [512]
#define WS_BKF (WS_BQF + 512)          // fused bk'' f32 [512]
#define WS_QBF (WS_BKF + 512)          // query bf16 [1024][512]; reused as X bf16 after proj
#define WS_KBF (WS_QBF + 262144)       // key bf16
#define WS_VBF (WS_KBF + 262144)       // value bf16
#define WS_WVB (WS_VBF + 262144)       // Wv bf16 [512][512]
#define WS_WOB (WS_WVB + 131072)       // Wo bf16 [512][512]
#define WS_EQ  (WS_WOB + 131072)       // EQ = exp2(Qt') f32 head-major [32bh][256][64]
#define WS_EK  (WS_EQ + 524288)        // EK = exp2(Kt') f32 head-major
#define WS_VF  (WS_EK + 524288)        // V bf16 MFMA B-fragments [32bh][32tile][64lane][8j]

typedef __attribute__((ext_vector_type(4))) float f32x4;
typedef __attribute__((ext_vector_type(8))) short bf16x8;

__device__ __forceinline__ short f2bf(float x) {
  unsigned u = __float_as_uint(x);
  u += 0x7fffu + ((u >> 16) & 1u);   // RNE
  return (short)(u >> 16);
}

// ---------------- prep: z=0/1 fold W1/W2 (+SCALE2) into Wq/Wk -> bf16; z=2..6 f32->bf16 copies
__global__ __launch_bounds__(256) void prep(
    const float* __restrict__ Wq, const float* __restrict__ bq,
    const float* __restrict__ Wk, const float* __restrict__ bk,
    const float* __restrict__ W1, const float* __restrict__ b1,
    const float* __restrict__ W2, const float* __restrict__ b2,
    const float* __restrict__ q, const float* __restrict__ k, const float* __restrict__ v,
    const float* __restrict__ Wv, const float* __restrict__ Wo,
    float* __restrict__ ws)
{
  const int z = blockIdx.z;
  if (z >= 2) {
    const int zz = z - 2;
    const float* src; short* dst; int n;
    if (zz == 0)      { src = q;  dst = (short*)(ws + WS_QBF); n = 524288; }
    else if (zz == 1) { src = k;  dst = (short*)(ws + WS_KBF); n = 524288; }
    else if (zz == 2) { src = v;  dst = (short*)(ws + WS_VBF); n = 524288; }
    else if (zz == 3) { src = Wv; dst = (short*)(ws + WS_WVB); n = 262144; }
    else              { src = Wo; dst = (short*)(ws + WS_WOB); n = 262144; }
    const int i = (blockIdx.x * 256 + threadIdx.x) * 8;
    if (i >= n) return;
    const float4 a = *reinterpret_cast<const float4*>(src + i);
    const float4 b = *reinterpret_cast<const float4*>(src + i + 4);
    bf16x8 o;
    o[0] = f2bf(a.x); o[1] = f2bf(a.y); o[2] = f2bf(a.z); o[3] = f2bf(a.w);
    o[4] = f2bf(b.x); o[5] = f2bf(b.y); o[6] = f2bf(b.z); o[7] = f2bf(b.w);
    *reinterpret_cast<bf16x8*>(dst + i) = o;
    return;
  }

  if (blockIdx.x >= 128) return;
  const int c0 = (blockIdx.x & 3) * 128;
  const int y  = blockIdx.x >> 2;
  const int h  = y >> 2;
  const int ig = y & 3;                // 16-row group within head
  const int which = z;
  const float* Wsrc = which ? Wk : Wq;
  const float* bsrc = which ? bk : bq;
  const float* Wt   = which ? W2 : W1;
  const float* bt   = which ? b2 : b1;
  short* Wout = reinterpret_cast<short*>(ws + (which ? WS_WKB : WS_WQB));
  float* bout = ws + (which ? WS_BKF : WS_BQF);

  __shared__ float Wtl[16][68];
  for (int t = threadIdx.x; t < 16*64; t += 256)
    Wtl[t >> 6][t & 63] = Wt[(ig*16 + (t >> 6))*64 + (t & 63)];
  __syncthreads();

  const int c  = c0 + (threadIdx.x & 127);
  const int i0 = (threadIdx.x >> 7) * 8;   // local row base (0 or 8)
  float acc[8];
#pragma unroll
  for (int ii = 0; ii < 8; ++ii) acc[ii] = 0.f;

  for (int j0 = 0; j0 < 64; j0 += 4) {
    const float s0 = Wsrc[(h*64 + j0 + 0)*HIDN + c];
    const float s1 = Wsrc[(h*64 + j0 + 1)*HIDN + c];
    const float s2 = Wsrc[(h*64 + j0 + 2)*HIDN + c];
    const float s3 = Wsrc[(h*64 + j0 + 3)*HIDN + c];
#pragma unroll
    for (int ii = 0; ii < 8; ++ii) {
      const float4 wv4 = *reinterpret_cast<const float4*>(&Wtl[i0+ii][j0]);
      float a = acc[ii];
      a = fmaf(wv4.x, s0, a);
      a = fmaf(wv4.y, s1, a);
      a = fmaf(wv4.z, s2, a);
      a = fmaf(wv4.w, s3, a);
      acc[ii] = a;
    }
  }
#pragma unroll
  for (int ii = 0; ii < 8; ++ii)
    Wout[(h*64 + ig*16 + i0 + ii)*HIDN + c] = f2bf(acc[ii] * SCALE2);

  if (blockIdx.x == 0 && threadIdx.x < 16) {
    const int il = threadIdx.x;
    float a = bt[ig*16 + il];
    for (int j = 0; j < 64; ++j)
      a = fmaf(Wtl[il][j], bsrc[h*64 + j], a);
    bout[h*64 + ig*16 + il] = a * SCALE2;
  }
}

// ---------------- mfma_proj: C = A(bf16) @ W(bf16)^T + bias ----------------
// LDS-free; 32-wide n-split (grid 16x16x3 = 3072 waves, 3/SIMD) for latency hiding.
// z=0 -> EQ = exp2(Qt'+b) f32; z=1 -> EK = exp2(Kt'+b) f32; z=2 -> VF bf16 fragments.
__global__ __launch_bounds__(256) void mfma_proj(float* __restrict__ ws, const float* __restrict__ bv)
{
  const int z = blockIdx.z;
  const short* A; const short* W; const float* bias;
  if (z == 0)      { A = (const short*)(ws + WS_QBF); W = (const short*)(ws + WS_WQB); bias = ws + WS_BQF; }
  else if (z == 1) { A = (const short*)(ws + WS_KBF); W = (const short*)(ws + WS_WKB); bias = ws + WS_BKF; }
  else             { A = (const short*)(ws + WS_VBF); W = (const short*)(ws + WS_WVB); bias = bv; }

  const int wid  = threadIdx.x >> 6;
  const int lane = threadIdx.x & 63;
  const int mt = blockIdx.y * 4 + wid;     // m-tile 0..63
  const int nb = blockIdx.x * 32;          // n base
  const short* aptr = A + (mt*16 + (lane & 15))*HIDN + (lane >> 4)*8;
  const short* wptr = W + (nb + (lane & 15))*HIDN + (lane >> 4)*8;

  f32x4 acc[2] = {{0,0,0,0},{0,0,0,0}};
#pragma unroll 4
  for (int k0 = 0; k0 < HIDN; k0 += 32) {
    const bf16x8 af = *reinterpret_cast<const bf16x8*>(aptr + k0);
    const short* wp = wptr + k0;
#pragma unroll
    for (int t = 0; t < 2; ++t)
      acc[t] = __builtin_amdgcn_mfma_f32_16x16x32_bf16(
          af, *reinterpret_cast<const bf16x8*>(wp + t*16*HIDN), acc[t], 0, 0, 0);
  }

  const int rbase = mt*16 + (lane >> 4)*4;
  if (z < 2) {
    // store EQ/EK = exp2(proj + bias); weights carry the 2*log2(e) prescale
    float* dst = ws + (z == 0 ? WS_EQ : WS_EK);
#pragma unroll
    for (int t = 0; t < 2; ++t) {
      const int c = nb + t*16 + (lane & 15);
      const float bc = bias[c];
      const int hh = c >> 6, d = c & 63;
#pragma unroll
      for (int r = 0; r < 4; ++r) {
        const int R = rbase + r;
        dst[(((R >> 8)*NHEAD + hh)*NL + (R & 255))*DHEAD + d] =
            __builtin_amdgcn_exp2f(acc[t][r] + bc);
      }
    }
  } else {
    short* vf = reinterpret_cast<short*>(ws + WS_VF);
#pragma unroll
    for (int t = 0; t < 2; ++t) {
      const int c = nb + t*16 + (lane & 15);
      const float bc = bias[c];
      const int hh = c >> 6, d = c & 63;
#pragma unroll
      for (int r = 0; r < 4; ++r) {
        const int R = rbase + r;
        const int l = R & 255;
        const int bh = (R >> 8)*NHEAD + hh;
        const int tile = ((l >> 5) << 2) + (d >> 4);
        const int lanep = (((l >> 3) & 3) << 4) + (d & 15);
        vf[((bh*32 + tile)*64 + lanep)*8 + (l & 7)] = f2bf(acc[t][r] + bc);
      }
    }
  }
}

// ---------------- mfma_out: out = X(bf16) @ Wo(bf16)^T + bo, f32 row-major ----------------
__global__ __launch_bounds__(256) void mfma_out(
    float* __restrict__ ws, const float* __restrict__ bo, float* __restrict__ out)
{
  const short* A = (const short*)(ws + WS_QBF);   // X bf16 (reused region)
  const short* W = (const short*)(ws + WS_WOB);
  const int wid  = threadIdx.x >> 6;
  const int lane = threadIdx.x & 63;
  const int mt = blockIdx.y * 4 + wid;     // 0..63
  const int nb = blockIdx.x * 32;          // 0..480
  const short* aptr = A + (mt*16 + (lane & 15))*HIDN + (lane >> 4)*8;
  const short* wptr = W + (nb + (lane & 15))*HIDN + (lane >> 4)*8;

  f32x4 acc[2] = {{0,0,0,0},{0,0,0,0}};
#pragma unroll 4
  for (int k0 = 0; k0 < HIDN; k0 += 32) {
    const bf16x8 af = *reinterpret_cast<const bf16x8*>(aptr + k0);
    const short* wp = wptr + k0;
#pragma unroll
    for (int t = 0; t < 2; ++t)
      acc[t] = __builtin_amdgcn_mfma_f32_16x16x32_bf16(
          af, *reinterpret_cast<const bf16x8*>(wp + t*16*HIDN), acc[t], 0, 0, 0);
  }

  const int rbase = mt*16 + (lane >> 4)*4;
#pragma unroll
  for (int t = 0; t < 2; ++t) {
    const int c = nb + t*16 + (lane & 15);
    const float bc = bo[c];
#pragma unroll
    for (int r = 0; r < 4; ++r)
      out[(rbase + r)*HIDN + c] = acc[t][r] + bc;
  }
}

// ---------------- attn: paired-rcp energy (SGPR Eq/va, no LDS in hot loop) ----------------
// grid (16 qtiles, 32 bh), 1024 threads. Group g=tid>>8 owns q-rows g*4..g*4+3;
// thread lk=tid&255 owns key lk. Eq rows & va are WAVE-UNIFORM -> scalar loads
// (s_load), keeping the LDS unit free for the P-fragment publish + PV only.
//   va0/t0 + va1/t1 = (va0*t1 + va1*t0) * rcp(t0*t1),  t = 1 + EQ*EK
//   e = -2 * sum(va_d * sigma'_d)  (const dropped; softmax shift-invariant)
__global__ __launch_bounds__(1024, 4) void attn_kernel(
    const float* __restrict__ eqB, const float* __restrict__ ekB,
    const short* __restrict__ vfB, const float* __restrict__ va_w,
    float* __restrict__ attn_out, short* __restrict__ xb)
{
  const int qt = blockIdx.x;
  const int bh = blockIdx.y;
  const int tid = threadIdx.x;

  __shared__ __align__(16) short aLb[8][64][8];      // 8 KB  P as bf16 A-fragments
  __shared__ __align__(16) float reds[4][4][4];      // [qgroup][wave][qi]

  const float* EKB = ekB + bh*NL*DHEAD;
  const short* VF  = vfB + bh*32*64*8;

  const int g  = tid >> 8;        // q-group: rows g*4 .. g*4+3 (wave-uniform)
  const int lk = tid & 255;
  const int wv = lk >> 6;
  const int l  = lk & 63;
  const float* EkRow = EKB + lk*DHEAD;
  // force scalar path for the wave-uniform Eq pointer
  const int g_u = __builtin_amdgcn_readfirstlane(g);
  const float* EqG = eqB + (bh*NL + qt*16 + g_u*4)*DHEAD;

  float acc[4];
#pragma unroll
  for (int qi = 0; qi < 4; ++qi) acc[qi] = 0.f;

#pragma unroll 1
  for (int d0 = 0; d0 < 64; d0 += 8) {
    const f32x4 ea = *reinterpret_cast<const f32x4*>(EkRow + d0);
    const f32x4 eb = *reinterpret_cast<const f32x4*>(EkRow + d0 + 4);
    const f32x4 vaA = *reinterpret_cast<const f32x4*>(va_w + d0);       // uniform -> SGPR
    const f32x4 vaB = *reinterpret_cast<const f32x4*>(va_w + d0 + 4);
#pragma unroll
    for (int qi = 0; qi < 4; ++qi) {
      const f32x4 qa = *reinterpret_cast<const f32x4*>(EqG + qi*DHEAD + d0);      // uniform
      const f32x4 qb = *reinterpret_cast<const f32x4*>(EqG + qi*DHEAD + d0 + 4);  // uniform
      const float t0 = fmaf(qa.x, ea.x, 1.0f);
      const float t1 = fmaf(qa.y, ea.y, 1.0f);
      const float t2 = fmaf(qa.z, ea.z, 1.0f);
      const float t3 = fmaf(qa.w, ea.w, 1.0f);
      const float t4 = fmaf(qb.x, eb.x, 1.0f);
      const float t5 = fmaf(qb.y, eb.y, 1.0f);
      const float t6 = fmaf(qb.z, eb.z, 1.0f);
      const float t7 = fmaf(qb.w, eb.w, 1.0f);
      float a = acc[qi];
      a = fmaf(fmaf(vaA.x, t1, vaA.y * t0), __builtin_amdgcn_rcpf(t0 * t1), a);
      a = fmaf(fmaf(vaA.z, t3, vaA.w * t2), __builtin_amdgcn_rcpf(t2 * t3), a);
      a = fmaf(fmaf(vaB.x, t5, vaB.y * t4), __builtin_amdgcn_rcpf(t4 * t5), a);
      a = fmaf(fmaf(vaB.z, t7, vaB.w * t6), __builtin_amdgcn_rcpf(t6 * t7), a);
      acc[qi] = a;
    }
  }

  // p = exp(-2*acc)  (|e| <= ~2*sum|va| ~ 8 -> no max shift needed)
  float p[4];
#pragma unroll
  for (int qi = 0; qi < 4; ++qi)
    p[qi] = __builtin_amdgcn_exp2f(acc[qi] * NEG2LOG2E);

#pragma unroll
  for (int qi = 0; qi < 4; ++qi) {
    float s = p[qi];
#pragma unroll
    for (int off = 1; off < 64; off <<= 1)
      s += __shfl_xor(s, off);
    if (l == 0) reds[g][wv][qi] = s;
  }
  // publish P as bf16 A-fragments
  {
    const int kb2 = lk >> 5;
    const int lbase = ((lk >> 3) & 3) * 16;
    const int jb = lk & 7;
#pragma unroll
    for (int qi = 0; qi < 4; ++qi)
      aLb[kb2][lbase + g*4 + qi][jb] = f2bf(p[qi]);
  }
  __syncthreads();

  // totals + attention output
  {
    f32x4 s4 = {0.f,0.f,0.f,0.f};
#pragma unroll
    for (int w2 = 0; w2 < 4; ++w2)
      s4 += *reinterpret_cast<const f32x4*>(&reds[g][w2][0]);
    float inv[4];
    inv[0] = __builtin_amdgcn_rcpf(s4.x); inv[1] = __builtin_amdgcn_rcpf(s4.y);
    inv[2] = __builtin_amdgcn_rcpf(s4.z); inv[3] = __builtin_amdgcn_rcpf(s4.w);
#pragma unroll
    for (int qi = 0; qi < 4; ++qi)
      attn_out[(bh*NL + qt*16 + g*4 + qi)*NL + lk] = p[qi] * inv[qi];

    // PV via MFMA: waves 0..3 (wid = d-block), V B-fragments from global (L2-hot)
    const int wid = tid >> 6;
    if (wid < 4) {
      f32x4 pacc = {0.f,0.f,0.f,0.f};
#pragma unroll
      for (int kb2 = 0; kb2 < 8; ++kb2) {
        const bf16x8 af  = *reinterpret_cast<const bf16x8*>(&aLb[kb2][l][0]);
        const bf16x8 bff = *reinterpret_cast<const bf16x8*>(&VF[((kb2*4 + wid)*64 + l)*8]);
        pacc = __builtin_amdgcn_mfma_f32_16x16x32_bf16(af, bff, pacc, 0, 0, 0);
      }
      const int b_ = bh >> 3, hh = bh & 7;
      const int colv = hh*DHEAD + wid*16 + (l & 15);
#pragma unroll
      for (int r = 0; r < 4; ++r) {
        const int row = (l >> 4)*4 + r;            // q index 0..15
        const float stot = reds[row>>2][0][row&3] + reds[row>>2][1][row&3]
                         + reds[row>>2][2][row&3] + reds[row>>2][3][row&3];
        xb[(b_*NL + qt*16 + row)*HIDN + colv] = f2bf(pacc[r] * __builtin_amdgcn_rcpf(stot));
      }
    }
  }
}

extern "C" void kernel_launch(void* const* d_in, const int* in_sizes, int n_in,
                              void* d_out, int out_size, void* d_ws, size_t ws_size,
                              hipStream_t stream) {
  const float* query = (const float*)d_in[0];
  const float* key   = (const float*)d_in[1];
  const float* value = (const float*)d_in[2];
  const float* Wq = (const float*)d_in[3];
  const float* bq = (const float*)d_in[4];
  const float* Wk = (const float*)d_in[5];
  const float* bk = (const float*)d_in[6];
  const float* Wv = (const float*)d_in[7];
  const float* bv = (const float*)d_in[8];
  const float* W1 = (const float*)d_in[9];
  const float* b1 = (const float*)d_in[10];
  const float* W2 = (const float*)d_in[11];
  const float* b2 = (const float*)d_in[12];
  const float* va_w = (const float*)d_in[13];
  const float* Wo = (const float*)d_in[15];
  const float* bo = (const float*)d_in[16];

  float* out = (float*)d_out;
  float* ws  = (float*)d_ws;
  float* attn = out + NROW*HIDN;   // output 1: attention [B,H,Lq,Lk]

  prep<<<dim3(256, 1, 7), 256, 0, stream>>>(Wq, bq, Wk, bk, W1, b1, W2, b2,
                                            query, key, value, Wv, Wo, ws);
  mfma_proj<<<dim3(16, 16, 3), 256, 0, stream>>>(ws, bv);
  attn_kernel<<<dim3(16, 32), 1024, 0, stream>>>(
      ws + WS_EQ, ws + WS_EK, (const short*)(ws + WS_VF), va_w,
      attn, (short*)(ws + WS_QBF));
  mfma_out<<<dim3(16, 16), 256, 0, stream>>>(ws, bo, out);
}

// Round 10
// 59.637 us; speedup vs baseline: 6.5783x; 1.0005x over previous
//
#include <hip/hip_runtime.h>

#define HIDN 512
#define NHEAD 8
#define DHEAD 64
#define NB 4
#define NL 256
#define NROW 1024   // NB*NL

// 2*log2(e): exp(2y) = exp2(y * SCALE2)
#define SCALE2 2.8853900817779268f
#define LOG2E  1.4426950408889634f
#define NEG2LOG2E -2.8853900817779268f

// workspace layout (float offsets)
#define WS_WQB 0                       // fused Wq'' bf16 [512][512]   (131072 floats)
#define WS_WKB (WS_WQB + 131072)       // fused Wk'' bf16
#define WS_BQF (WS_WKB + 131072)       // fused bq'' f32 [512]
#define WS_BKF (WS_BQF + 512)          // fused bk'' f32 [512]
#define WS_QBF (WS_BKF + 512)          // query bf16 [1024][512]; reused as X bf16 after proj
#define WS_KBF (WS_QBF + 262144)       // key bf16
#define WS_VBF (WS_KBF + 262144)       // value bf16
#define WS_WVB (WS_VBF + 262144)       // Wv bf16 [512][512]
#define WS_WOB (WS_WVB + 131072)       // Wo bf16 [512][512]
#define WS_EQ  (WS_WOB + 131072)       // EQ = exp2(Qt') f32 head-major [32bh][256][64]
#define WS_EK  (WS_EQ + 524288)        // EK = exp2(Kt') f32 head-major
#define WS_VF  (WS_EK + 524288)        // V bf16 MFMA B-fragments [32bh][32tile][64lane][8j]

typedef __attribute__((ext_vector_type(4))) float f32x4;
typedef __attribute__((ext_vector_type(8))) short bf16x8;

__device__ __forceinline__ short f2bf(float x) {
  unsigned u = __float_as_uint(x);
  u += 0x7fffu + ((u >> 16) & 1u);   // RNE
  return (short)(u >> 16);
}

// ---------------- prep: z=0/1 fold W1/W2 (+SCALE2) into Wq/Wk -> bf16; z=2..6 f32->bf16 copies
__global__ __launch_bounds__(256) void prep(
    const float* __restrict__ Wq, const float* __restrict__ bq,
    const float* __restrict__ Wk, const float* __restrict__ bk,
    const float* __restrict__ W1, const float* __restrict__ b1,
    const float* __restrict__ W2, const float* __restrict__ b2,
    const float* __restrict__ q, const float* __restrict__ k, const float* __restrict__ v,
    const float* __restrict__ Wv, const float* __restrict__ Wo,
    float* __restrict__ ws)
{
  const int z = blockIdx.z;
  if (z >= 2) {
    const int zz = z - 2;
    const float* src; short* dst; int n;
    if (zz == 0)      { src = q;  dst = (short*)(ws + WS_QBF); n = 524288; }
    else if (zz == 1) { src = k;  dst = (short*)(ws + WS_KBF); n = 524288; }
    else if (zz == 2) { src = v;  dst = (short*)(ws + WS_VBF); n = 524288; }
    else if (zz == 3) { src = Wv; dst = (short*)(ws + WS_WVB); n = 262144; }
    else              { src = Wo; dst = (short*)(ws + WS_WOB); n = 262144; }
    const int i = (blockIdx.x * 256 + threadIdx.x) * 8;
    if (i >= n) return;
    const float4 a = *reinterpret_cast<const float4*>(src + i);
    const float4 b = *reinterpret_cast<const float4*>(src + i + 4);
    bf16x8 o;
    o[0] = f2bf(a.x); o[1] = f2bf(a.y); o[2] = f2bf(a.z); o[3] = f2bf(a.w);
    o[4] = f2bf(b.x); o[5] = f2bf(b.y); o[6] = f2bf(b.z); o[7] = f2bf(b.w);
    *reinterpret_cast<bf16x8*>(dst + i) = o;
    return;
  }

  if (blockIdx.x >= 128) return;
  const int c0 = (blockIdx.x & 3) * 128;
  const int y  = blockIdx.x >> 2;
  const int h  = y >> 2;
  const int ig = y & 3;                // 16-row group within head
  const int which = z;
  const float* Wsrc = which ? Wk : Wq;
  const float* bsrc = which ? bk : bq;
  const float* Wt   = which ? W2 : W1;
  const float* bt   = which ? b2 : b1;
  short* Wout = reinterpret_cast<short*>(ws + (which ? WS_WKB : WS_WQB));
  float* bout = ws + (which ? WS_BKF : WS_BQF);

  __shared__ float Wtl[16][68];
  for (int t = threadIdx.x; t < 16*64; t += 256)
    Wtl[t >> 6][t & 63] = Wt[(ig*16 + (t >> 6))*64 + (t & 63)];
  __syncthreads();

  const int c  = c0 + (threadIdx.x & 127);
  const int i0 = (threadIdx.x >> 7) * 8;   // local row base (0 or 8)
  float acc[8];
#pragma unroll
  for (int ii = 0; ii < 8; ++ii) acc[ii] = 0.f;

  for (int j0 = 0; j0 < 64; j0 += 4) {
    const float s0 = Wsrc[(h*64 + j0 + 0)*HIDN + c];
    const float s1 = Wsrc[(h*64 + j0 + 1)*HIDN + c];
    const float s2 = Wsrc[(h*64 + j0 + 2)*HIDN + c];
    const float s3 = Wsrc[(h*64 + j0 + 3)*HIDN + c];
#pragma unroll
    for (int ii = 0; ii < 8; ++ii) {
      const float4 wv4 = *reinterpret_cast<const float4*>(&Wtl[i0+ii][j0]);
      float a = acc[ii];
      a = fmaf(wv4.x, s0, a);
      a = fmaf(wv4.y, s1, a);
      a = fmaf(wv4.z, s2, a);
      a = fmaf(wv4.w, s3, a);
      acc[ii] = a;
    }
  }
#pragma unroll
  for (int ii = 0; ii < 8; ++ii)
    Wout[(h*64 + ig*16 + i0 + ii)*HIDN + c] = f2bf(acc[ii] * SCALE2);

  if (blockIdx.x == 0 && threadIdx.x < 16) {
    const int il = threadIdx.x;
    float a = bt[ig*16 + il];
    for (int j = 0; j < 64; ++j)
      a = fmaf(Wtl[il][j], bsrc[h*64 + j], a);
    bout[h*64 + ig*16 + il] = a * SCALE2;
  }
}

// ---------------- mfma_proj: C = A(bf16) @ W(bf16)^T + bias ----------------
// LDS-free; 32-wide n-split (grid 16x16x3 = 3072 waves, 3/SIMD) for latency hiding.
// z=0 -> EQ = exp2(Qt'+b) f32; z=1 -> EK = exp2(Kt'+b) f32; z=2 -> VF bf16 fragments.
__global__ __launch_bounds__(256) void mfma_proj(float* __restrict__ ws, const float* __restrict__ bv)
{
  const int z = blockIdx.z;
  const short* A; const short* W; const float* bias;
  if (z == 0)      { A = (const short*)(ws + WS_QBF); W = (const short*)(ws + WS_WQB); bias = ws + WS_BQF; }
  else if (z == 1) { A = (const short*)(ws + WS_KBF); W = (const short*)(ws + WS_WKB); bias = ws + WS_BKF; }
  else             { A = (const short*)(ws + WS_VBF); W = (const short*)(ws + WS_WVB); bias = bv; }

  const int wid  = threadIdx.x >> 6;
  const int lane = threadIdx.x & 63;
  const int mt = blockIdx.y * 4 + wid;     // m-tile 0..63
  const int nb = blockIdx.x * 32;          // n base
  const short* aptr = A + (mt*16 + (lane & 15))*HIDN + (lane >> 4)*8;
  const short* wptr = W + (nb + (lane & 15))*HIDN + (lane >> 4)*8;

  f32x4 acc[2] = {{0,0,0,0},{0,0,0,0}};
#pragma unroll 4
  for (int k0 = 0; k0 < HIDN; k0 += 32) {
    const bf16x8 af = *reinterpret_cast<const bf16x8*>(aptr + k0);
    const short* wp = wptr + k0;
#pragma unroll
    for (int t = 0; t < 2; ++t)
      acc[t] = __builtin_amdgcn_mfma_f32_16x16x32_bf16(
          af, *reinterpret_cast<const bf16x8*>(wp + t*16*HIDN), acc[t], 0, 0, 0);
  }

  const int rbase = mt*16 + (lane >> 4)*4;
  if (z < 2) {
    // store EQ/EK = exp2(proj + bias); weights carry the 2*log2(e) prescale
    float* dst = ws + (z == 0 ? WS_EQ : WS_EK);
#pragma unroll
    for (int t = 0; t < 2; ++t) {
      const int c = nb + t*16 + (lane & 15);
      const float bc = bias[c];
      const int hh = c >> 6, d = c & 63;
#pragma unroll
      for (int r = 0; r < 4; ++r) {
        const int R = rbase + r;
        dst[(((R >> 8)*NHEAD + hh)*NL + (R & 255))*DHEAD + d] =
            __builtin_amdgcn_exp2f(acc[t][r] + bc);
      }
    }
  } else {
    short* vf = reinterpret_cast<short*>(ws + WS_VF);
#pragma unroll
    for (int t = 0; t < 2; ++t) {
      const int c = nb + t*16 + (lane & 15);
      const float bc = bias[c];
      const int hh = c >> 6, d = c & 63;
#pragma unroll
      for (int r = 0; r < 4; ++r) {
        const int R = rbase + r;
        const int l = R & 255;
        const int bh = (R >> 8)*NHEAD + hh;
        const int tile = ((l >> 5) << 2) + (d >> 4);
        const int lanep = (((l >> 3) & 3) << 4) + (d & 15);
        vf[((bh*32 + tile)*64 + lanep)*8 + (l & 7)] = f2bf(acc[t][r] + bc);
      }
    }
  }
}

// ---------------- mfma_out: out = X(bf16) @ Wo(bf16)^T + bo, f32 row-major ----------------
__global__ __launch_bounds__(256) void mfma_out(
    float* __restrict__ ws, const float* __restrict__ bo, float* __restrict__ out)
{
  const short* A = (const short*)(ws + WS_QBF);   // X bf16 (reused region)
  const short* W = (const short*)(ws + WS_WOB);
  const int wid  = threadIdx.x >> 6;
  const int lane = threadIdx.x & 63;
  const int mt = blockIdx.y * 4 + wid;     // 0..63
  const int nb = blockIdx.x * 32;          // 0..480
  const short* aptr = A + (mt*16 + (lane & 15))*HIDN + (lane >> 4)*8;
  const short* wptr = W + (nb + (lane & 15))*HIDN + (lane >> 4)*8;

  f32x4 acc[2] = {{0,0,0,0},{0,0,0,0}};
#pragma unroll 4
  for (int k0 = 0; k0 < HIDN; k0 += 32) {
    const bf16x8 af = *reinterpret_cast<const bf16x8*>(aptr + k0);
    const short* wp = wptr + k0;
#pragma unroll
    for (int t = 0; t < 2; ++t)
      acc[t] = __builtin_amdgcn_mfma_f32_16x16x32_bf16(
          af, *reinterpret_cast<const bf16x8*>(wp + t*16*HIDN), acc[t], 0, 0, 0);
  }

  const int rbase = mt*16 + (lane >> 4)*4;
#pragma unroll
  for (int t = 0; t < 2; ++t) {
    const int c = nb + t*16 + (lane & 15);
    const float bc = bo[c];
#pragma unroll
    for (int r = 0; r < 4; ++r)
      out[(rbase + r)*HIDN + c] = acc[t][r] + bc;
  }
}

// ---------------- attn: paired-rcp energy (SGPR Eq/va, no LDS in hot loop) ----------------
// grid (16 qtiles, 32 bh), 1024 threads. (1024, 8): force VGPR<=64 so TWO 1024-thread
// blocks fit per CU (8 waves/SIMD) -- at (1024,4) the allocator may exceed 64 VGPR and
// silently halve occupancy (m69: waves/CU halve at >64).
//   va0/t0 + va1/t1 = (va0*t1 + va1*t0) * rcp(t0*t1),  t = 1 + EQ*EK
//   e = -2 * sum(va_d * sigma'_d)  (const dropped; softmax shift-invariant)
__global__ __launch_bounds__(1024, 8) void attn_kernel(
    const float* __restrict__ eqB, const float* __restrict__ ekB,
    const short* __restrict__ vfB, const float* __restrict__ va_w,
    float* __restrict__ attn_out, short* __restrict__ xb)
{
  const int qt = blockIdx.x;
  const int bh = blockIdx.y;
  const int tid = threadIdx.x;

  __shared__ __align__(16) short aLb[8][64][8];      // 8 KB  P as bf16 A-fragments
  __shared__ __align__(16) float reds[4][4][4];      // [qgroup][wave][qi]

  const float* EKB = ekB + bh*NL*DHEAD;
  const short* VF  = vfB + bh*32*64*8;

  const int g  = tid >> 8;        // q-group: rows g*4 .. g*4+3 (wave-uniform)
  const int lk = tid & 255;
  const int wv = lk >> 6;
  const int l  = lk & 63;
  const float* EkRow = EKB + lk*DHEAD;
  // force scalar path for the wave-uniform Eq pointer
  const int g_u = __builtin_amdgcn_readfirstlane(g);
  const float* EqG = eqB + (bh*NL + qt*16 + g_u*4)*DHEAD;

  float acc[4];
#pragma unroll
  for (int qi = 0; qi < 4; ++qi) acc[qi] = 0.f;

#pragma unroll 1
  for (int d0 = 0; d0 < 64; d0 += 8) {
    const f32x4 ea = *reinterpret_cast<const f32x4*>(EkRow + d0);
    const f32x4 eb = *reinterpret_cast<const f32x4*>(EkRow + d0 + 4);
    const f32x4 vaA = *reinterpret_cast<const f32x4*>(va_w + d0);       // uniform -> SGPR
    const f32x4 vaB = *reinterpret_cast<const f32x4*>(va_w + d0 + 4);
#pragma unroll
    for (int qi = 0; qi < 4; ++qi) {
      const f32x4 qa = *reinterpret_cast<const f32x4*>(EqG + qi*DHEAD + d0);      // uniform
      const f32x4 qb = *reinterpret_cast<const f32x4*>(EqG + qi*DHEAD + d0 + 4);  // uniform
      const float t0 = fmaf(qa.x, ea.x, 1.0f);
      const float t1 = fmaf(qa.y, ea.y, 1.0f);
      const float t2 = fmaf(qa.z, ea.z, 1.0f);
      const float t3 = fmaf(qa.w, ea.w, 1.0f);
      const float t4 = fmaf(qb.x, eb.x, 1.0f);
      const float t5 = fmaf(qb.y, eb.y, 1.0f);
      const float t6 = fmaf(qb.z, eb.z, 1.0f);
      const float t7 = fmaf(qb.w, eb.w, 1.0f);
      float a = acc[qi];
      a = fmaf(fmaf(vaA.x, t1, vaA.y * t0), __builtin_amdgcn_rcpf(t0 * t1), a);
      a = fmaf(fmaf(vaA.z, t3, vaA.w * t2), __builtin_amdgcn_rcpf(t2 * t3), a);
      a = fmaf(fmaf(vaB.x, t5, vaB.y * t4), __builtin_amdgcn_rcpf(t4 * t5), a);
      a = fmaf(fmaf(vaB.z, t7, vaB.w * t6), __builtin_amdgcn_rcpf(t6 * t7), a);
      acc[qi] = a;
    }
  }

  // p = exp(-2*acc)  (|e| <= ~2*sum|va| ~ 8 -> no max shift needed)
  float p[4];
#pragma unroll
  for (int qi = 0; qi < 4; ++qi)
    p[qi] = __builtin_amdgcn_exp2f(acc[qi] * NEG2LOG2E);

#pragma unroll
  for (int qi = 0; qi < 4; ++qi) {
    float s = p[qi];
#pragma unroll
    for (int off = 1; off < 64; off <<= 1)
      s += __shfl_xor(s, off);
    if (l == 0) reds[g][wv][qi] = s;
  }
  // publish P as bf16 A-fragments
  {
    const int kb2 = lk >> 5;
    const int lbase = ((lk >> 3) & 3) * 16;
    const int jb = lk & 7;
#pragma unroll
    for (int qi = 0; qi < 4; ++qi)
      aLb[kb2][lbase + g*4 + qi][jb] = f2bf(p[qi]);
  }
  __syncthreads();

  // totals + attention output
  {
    f32x4 s4 = {0.f,0.f,0.f,0.f};
#pragma unroll
    for (int w2 = 0; w2 < 4; ++w2)
      s4 += *reinterpret_cast<const f32x4*>(&reds[g][w2][0]);
    float inv[4];
    inv[0] = __builtin_amdgcn_rcpf(s4.x); inv[1] = __builtin_amdgcn_rcpf(s4.y);
    inv[2] = __builtin_amdgcn_rcpf(s4.z); inv[3] = __builtin_amdgcn_rcpf(s4.w);
#pragma unroll
    for (int qi = 0; qi < 4; ++qi)
      attn_out[(bh*NL + qt*16 + g*4 + qi)*NL + lk] = p[qi] * inv[qi];

    // PV via MFMA: waves 0..3 (wid = d-block), V B-fragments from global (L2-hot)
    const int wid = tid >> 6;
    if (wid < 4) {
      f32x4 pacc = {0.f,0.f,0.f,0.f};
#pragma unroll
      for (int kb2 = 0; kb2 < 8; ++kb2) {
        const bf16x8 af  = *reinterpret_cast<const bf16x8*>(&aLb[kb2][l][0]);
        const bf16x8 bff = *reinterpret_cast<const bf16x8*>(&VF[((kb2*4 + wid)*64 + l)*8]);
        pacc = __builtin_amdgcn_mfma_f32_16x16x32_bf16(af, bff, pacc, 0, 0, 0);
      }
      const int b_ = bh >> 3, hh = bh & 7;
      const int colv = hh*DHEAD + wid*16 + (l & 15);
#pragma unroll
      for (int r = 0; r < 4; ++r) {
        const int row = (l >> 4)*4 + r;            // q index 0..15
        const float stot = reds[row>>2][0][row&3] + reds[row>>2][1][row&3]
                         + reds[row>>2][2][row&3] + reds[row>>2][3][row&3];
        xb[(b_*NL + qt*16 + row)*HIDN + colv] = f2bf(pacc[r] * __builtin_amdgcn_rcpf(stot));
      }
    }
  }
}

extern "C" void kernel_launch(void* const* d_in, const int* in_sizes, int n_in,
                              void* d_out, int out_size, void* d_ws, size_t ws_size,
                              hipStream_t stream) {
  const float* query = (const float*)d_in[0];
  const float* key   = (const float*)d_in[1];
  const float* value = (const float*)d_in[2];
  const float* Wq = (const float*)d_in[3];
  const float* bq = (const float*)d_in[4];
  const float* Wk = (const float*)d_in[5];
  const float* bk = (const float*)d_in[6];
  const float* Wv = (const float*)d_in[7];
  const float* bv = (const float*)d_in[8];
  const float* W1 = (const float*)d_in[9];
  const float* b1 = (const float*)d_in[10];
  const float* W2 = (const float*)d_in[11];
  const float* b2 = (const float*)d_in[12];
  const float* va_w = (const float*)d_in[13];
  const float* Wo = (const float*)d_in[15];
  const float* bo = (const float*)d_in[16];

  float* out = (float*)d_out;
  float* ws  = (float*)d_ws;
  float* attn = out + NROW*HIDN;   // output 1: attention [B,H,Lq,Lk]

  prep<<<dim3(256, 1, 7), 256, 0, stream>>>(Wq, bq, Wk, bk, W1, b1, W2, b2,
                                            query, key, value, Wv, Wo, ws);
  mfma_proj<<<dim3(16, 16, 3), 256, 0, stream>>>(ws, bv);
  attn_kernel<<<dim3(16, 32), 1024, 0, stream>>>(
      ws + WS_EQ, ws + WS_EK, (const short*)(ws + WS_VF), va_w,
      attn, (short*)(ws + WS_QBF));
  mfma_out<<<dim3(16, 16), 256, 0, stream>>>(ws, bo, out);
}